// Round 6
// baseline (258.509 us; speedup 1.0000x reference)
//
#include <hip/hip_runtime.h>

// SSIM_13443247637111 — fused separable SSIM, V-first ring-buffer design.
// B=16, CH=3, 512x512, 11x11 gaussian sigma 1.5, zero padding 5.
//
// Round-8 structure (V revert + streaming H):
//  - ROUND-5 POST-MORTEM: V float2 put every lane on an EVEN bank
//    (addr = sr*336 + hq*8 -> bank = (2hq + 20*drow) mod 32, always even)
//    -> >=4-way conflicts; +6e6 conflict-cycles == the whole +12us
//    regression. V phase REVERTED to the proven Round-4 float4 form
//    (160 threads x 20 quads, full-bank b128 pattern).
//  - H phase KEPT as convg4s float4 streaming (bit-exact in Round-5 run):
//    50 wave b128-insts/super vs 140 b64-insts for the old float2-H
//    (~-240 LDS cyc/super), and full 32-bank coverage where float2-H was
//    even-bank-only.
//  - Everything else frozen: premask design, 2 rings + 5 fld = 25.6 KB LDS,
//    __launch_bounds__(256,4) (VGPR 60, no spill), grid 8x8x48 = 3072.

#define BATCH 16
#define CHANS 3
#define IMH 512
#define IMW 512
#define STRIPW 64
#define STRIPH 64
#define RINGR 18            // raw rows resident: y-5 .. y+12 for an 8-row super
#define LDSW 84             // padded row width; col c <-> x = bx*64 + c - 8
#define SUP 8               // output rows per super-iteration
#define NSUP (STRIPH / SUP) // 8
#define NQ 20               // float4 quads per staged row (80 cols)

// mask-pass tile
#define MTW 64
#define MTH 64
#define MRAWH 74            // MTH + 10 halo rows

__device__ __forceinline__ float4 ld4s(const float* p) { return *(const float4*)p; }
__device__ __forceinline__ void st4s(float* p, float4 v) { *(float4*)p = v; }
__device__ __forceinline__ void fma4(float4& a, float w, float4 x) {
    a.x = fmaf(w, x.x, a.x); a.y = fmaf(w, x.y, a.y);
    a.z = fmaf(w, x.z, a.z); a.w = fmaf(w, x.w, a.w);
}
__device__ __forceinline__ void fma4m(float4& a, float w, float4 x, float4 y) {
    a.x = fmaf(w, x.x * y.x, a.x); a.y = fmaf(w, x.y * y.y, a.y);
    a.z = fmaf(w, x.z * y.z, a.z); a.w = fmaf(w, x.w * y.w, a.w);
}
__device__ __forceinline__ void add4(float4& a, float4 x) {
    a.x += x.x; a.y += x.y; a.z += x.z; a.w += x.w;
}

// gaussian-weighted horizontal 11-tap conv, STREAMING form: 4 outputs from
// 5 float4 quads, only one quad live at a time (low register pressure).
// Per-output accumulation order is ascending-k -> bit-identical to convg.
// Harness-verified bit-exact in round-5 run.
__device__ __forceinline__ void convg4s(const float* __restrict__ row, int cb,
                                        const float* __restrict__ g, float out[4]) {
    out[0] = 0.0f; out[1] = 0.0f; out[2] = 0.0f; out[3] = 0.0f;
    #pragma unroll
    for (int i = 0; i < 5; ++i) {
        float4 v = ld4s(row + cb + 4 * i);
        float vv[4] = {v.x, v.y, v.z, v.w};
        #pragma unroll
        for (int e = 0; e < 4; ++e) {
            const int m = 4 * i + e;        // window index 0..19
            #pragma unroll
            for (int j = 0; j < 4; ++j) {
                const int k = m - 3 - j;    // tap index for output j
                if (k >= 0 && k <= 10)
                    out[j] = fmaf(g[k], vv[e], out[j]);
            }
        }
    }
}

// classic 20-float-window forms (mask_pass / fallback kernel only)
__device__ __forceinline__ void convg(const float* __restrict__ row, int cb,
                                      const float* __restrict__ g, float out[4]) {
    float w[20];
    #pragma unroll
    for (int i = 0; i < 5; ++i) {
        float4 v = ld4s(row + cb + 4 * i);
        w[4*i+0] = v.x; w[4*i+1] = v.y; w[4*i+2] = v.z; w[4*i+3] = v.w;
    }
    #pragma unroll
    for (int j = 0; j < 4; ++j) {
        float a = 0.0f;
        #pragma unroll
        for (int k = 0; k < 11; ++k) a = fmaf(g[k], w[3 + j + k], a);
        out[j] = a;
    }
}

__device__ __forceinline__ void convb(const float* __restrict__ row, int cb,
                                      float out[4]) {
    float w[20];
    #pragma unroll
    for (int i = 0; i < 5; ++i) {
        float4 v = ld4s(row + cb + 4 * i);
        w[4*i+0] = v.x; w[4*i+1] = v.y; w[4*i+2] = v.z; w[4*i+3] = v.w;
    }
    #pragma unroll
    for (int j = 0; j < 4; ++j) {
        float a = 0.0f;
        #pragma unroll
        for (int k = 0; k < 11; ++k) a += w[3 + j + k];
        out[j] = a;
    }
}

// ---------------------------------------------------------------------------
// mask precompute: box-filter match (11x11), threshold, store uint8 per pixel.
// Also accumulates the full denominator sum(mask) into acc[1].
// ---------------------------------------------------------------------------
__global__ __launch_bounds__(256) void mask_pass(
    const float* __restrict__ match, unsigned char* __restrict__ maskbuf,
    double* __restrict__ acc)
{
    __shared__ __align__(16) float raw[MRAWH][LDSW];
    __shared__ __align__(16) float vs[MTH][LDSW];
    __shared__ float red[4];

    const int tid = threadIdx.x;
    const int b = blockIdx.z;
    const int x0 = blockIdx.x * MTW - 8;     // global x of LDS col 0 (aligned)
    const int y0 = blockIdx.y * MTH - 5;
    const float* pm = match + (size_t)b * (IMH * IMW);

    // stage 74 rows x 20 quads (cols x0 .. x0+79), zero pad OOB
    for (int t = tid; t < MRAWH * NQ; t += 256) {
        int r = t / NQ, q = t - r * NQ;
        int gy = y0 + r;
        int gx = x0 + 4 * q;
        float4 v = make_float4(0.f, 0.f, 0.f, 0.f);
        if ((unsigned)gy < IMH) {
            if ((unsigned)gx <= (IMW - 4)) {
                v = ld4s(pm + gy * IMW + gx);
            } else {
                float tmp[4];
                #pragma unroll
                for (int e = 0; e < 4; ++e) {
                    int x = gx + e;
                    bool ok = (unsigned)x < IMW;
                    tmp[e] = ok ? pm[gy * IMW + x] : 0.0f;
                }
                v = make_float4(tmp[0], tmp[1], tmp[2], tmp[3]);
            }
        }
        st4s(&raw[r][4 * q], v);
    }
    __syncthreads();

    // vertical box: 64 rows x 20 quads
    for (int t = tid; t < MTH * NQ; t += 256) {
        int r = t / NQ, q = t - r * NQ;
        int cq = 4 * q;
        float4 a = make_float4(0.f, 0.f, 0.f, 0.f);
        #pragma unroll
        for (int k = 0; k < 11; ++k) add4(a, ld4s(&raw[r + k][cq]));
        st4s(&vs[r][cq], a);
    }
    __syncthreads();

    // horizontal box + threshold: 64 rows x 16 quads
    float den = 0.0f;
    for (int t = tid; t < MTH * 16; t += 256) {
        int r = t >> 4, q = t & 15;
        float mb[4];
        convb(vs[r], 4 * q, mb);
        unsigned char bits[4];
        #pragma unroll
        for (int j = 0; j < 4; ++j) {
            float m = mb[j] * (1.0f / 121.0f) + 1e-7f;
            bool on = m > 0.5f;
            bits[j] = (unsigned char)on;
            den += on ? (1.0f + 1e-7f) : 1e-7f;
        }
        int gy = blockIdx.y * MTH + r;
        int gx = blockIdx.x * MTW + 4 * q;
        *(uchar4*)(maskbuf + ((size_t)b << 18) + (gy << 9) + gx) =
            make_uchar4(bits[0], bits[1], bits[2], bits[3]);
    }

    for (int off = 32; off > 0; off >>= 1) den += __shfl_down(den, off);
    if ((tid & 63) == 0) red[tid >> 6] = den;
    __syncthreads();
    if (tid == 0)
        atomicAdd(&acc[1], (double)(red[0] + red[1] + red[2] + red[3]));
}

// ---------------------------------------------------------------------------
// main SSIM kernel: 2 rings + 5 fld arrays, LDS 25.6 KB.
// V phase: 160 threads x float4 (round-4 proven). H phase: 128 threads x
// float4 streaming (convg4s). Grid 8x8x48 = 3072 blocks.
// ---------------------------------------------------------------------------
__global__ __launch_bounds__(256, 4) void ssim_main_pm(
    const float* __restrict__ img1, const float* __restrict__ img2,
    const unsigned char* __restrict__ maskbuf,
    const float* __restrict__ gw, double* __restrict__ acc)
{
    __shared__ __align__(16) float ring1[RINGR][LDSW];
    __shared__ __align__(16) float ring2[RINGR][LDSW];
    __shared__ __align__(16) float fld[5][SUP][LDSW];
    __shared__ float redn[4];

    const int tid = threadIdx.x;
    const int bc = blockIdx.z;
    const int b = bc / CHANS;
    const int c = bc - b * CHANS;
    const int ystart = blockIdx.y * STRIPH;
    const int bxg = blockIdx.x;
    const int bx0 = bxg * STRIPW - 8;   // global x of LDS col 0

    const float* p1 = img1 + (size_t)(b * CHANS + c) * (IMH * IMW);
    const float* p2 = img2 + (size_t)(b * CHANS + c) * (IMH * IMW);
    const unsigned char* pmk = maskbuf + ((size_t)b << 18);

    // weights: uniform pointer + constant offsets -> scalar loads (SGPRs),
    // bit-identical to the expf sequence the reference-matched kernels used.
    float g[11];
    #pragma unroll
    for (int i = 0; i < 11; ++i) g[i] = gw[i];

    float num = 0.0f;
    const bool colsafe = (bx0 >= 0) && (bx0 + 4 * NQ <= IMW);  // interior in x

    auto stage = [&](int gy0, int nrows) {
        // nrows*NQ <= 200 < 256: single shot, no loop
        if (tid < nrows * NQ) {
            int r = tid / NQ, q = tid - r * NQ;
            int gy = gy0 + r;
            int slot = (gy + 36) % RINGR;
            int gx = bx0 + 4 * q;
            float4 v1 = make_float4(0.f, 0.f, 0.f, 0.f), v2 = v1;
            if ((unsigned)gy < IMH) {
                if (colsafe || (unsigned)gx <= (IMW - 4)) {
                    v1 = ld4s(p1 + gy * IMW + gx);
                    v2 = ld4s(p2 + gy * IMW + gx);
                } else {
                    float t1[4], t2[4];
                    #pragma unroll
                    for (int e = 0; e < 4; ++e) {
                        int x = gx + e;
                        bool ok = (unsigned)x < IMW;
                        int off = gy * IMW + (ok ? x : 0);
                        t1[e] = ok ? p1[off] : 0.0f;
                        t2[e] = ok ? p2[off] : 0.0f;
                    }
                    v1 = make_float4(t1[0], t1[1], t1[2], t1[3]);
                    v2 = make_float4(t2[0], t2[1], t2[2], t2[3]);
                }
            }
            st4s(&ring1[slot][4 * q], v1);
            st4s(&ring2[slot][4 * q], v2);
        }
    };

    // prologue: raw rows ystart-5 .. ystart+4
    stage(ystart - 5, 10);

    for (int s = 0; s < NSUP; ++s) {
        const int ybase = ystart + s * SUP;

        // stage the 8 new raw rows this super needs (ybase+5 .. ybase+12).
        // safe: slots being overwritten were last read by V of super s-1,
        // which completed before barrier B2 of super s-1.
        stage(ybase + 5, SUP);
        __syncthreads();   // B1: staging visible; fld free (H of s-1 done)

        // ---- vertical pass: 8 rows x 20 quads (80 cols incl. halo) ----
        if (tid < SUP * NQ) {
            int r = tid / NQ, q = tid - r * NQ;
            int cq = 4 * q;
            int sr = (ybase + r + 31) % RINGR;   // row (y-5)
            float4 a1 = make_float4(0,0,0,0), a2 = a1, a3 = a1,
                   a4 = a1, a5 = a1;
            #pragma unroll
            for (int k = 0; k < 11; ++k) {
                float4 x1 = ld4s(&ring1[sr][cq]);
                float4 x2 = ld4s(&ring2[sr][cq]);
                float w = g[k];
                fma4(a1, w, x1);
                fma4(a2, w, x2);
                fma4m(a3, w, x1, x1);
                fma4m(a4, w, x2, x2);
                fma4m(a5, w, x1, x2);
                sr++; if (sr >= RINGR) sr -= RINGR;
            }
            st4s(&fld[0][r][cq], a1);
            st4s(&fld[1][r][cq], a2);
            st4s(&fld[2][r][cq], a3);
            st4s(&fld[3][r][cq], a4);
            st4s(&fld[4][r][cq], a5);
        }
        __syncthreads();   // B2: fld visible; ring free for next stage

        // ---- horizontal pass + SSIM: 8 rows x 16 quads (128 thr) ----
        if (tid < SUP * 16) {
            int r = tid >> 4, q = tid & 15;
            int cb = 4 * q;   // window w[0] = col 4q; outputs at cols 4q+8..11
            float mu1[4], mu2[4], m11[4], m22[4], m12[4];
            convg4s(fld[0][r], cb, g, mu1);
            convg4s(fld[1][r], cb, g, mu2);
            convg4s(fld[2][r], cb, g, m11);
            convg4s(fld[3][r], cb, g, m22);
            convg4s(fld[4][r], cb, g, m12);
            int gy = ybase + r;
            int gx = bxg * STRIPW + cb;
            uchar4 mk = *(const uchar4*)(pmk + (gy << 9) + gx);
            const unsigned char mkv[4] = {mk.x, mk.y, mk.z, mk.w};
            #pragma unroll
            for (int j = 0; j < 4; ++j) {
                float mu1s = mu1[j] * mu1[j];
                float mu2s = mu2[j] * mu2[j];
                float mu12 = mu1[j] * mu2[j];
                float sg1  = m11[j] - mu1s;
                float sg2  = m22[j] - mu2s;
                float sg12 = m12[j] - mu12;
                float ssim = ((2.0f * mu12 + 1e-4f) * (2.0f * sg12 + 9e-4f)) /
                             ((mu1s + mu2s + 1e-4f) * (sg1 + sg2 + 9e-4f));
                float mask = mkv[j] ? (1.0f + 1e-7f) : 1e-7f;
                num += (1.0f - ssim) * mask;
            }
        }
    }

    // ---- block reduction: wave shuffle (width 64) then cross-wave LDS ----
    for (int off = 32; off > 0; off >>= 1) num += __shfl_down(num, off);
    if ((tid & 63) == 0) redn[tid >> 6] = num;
    __syncthreads();
    if (tid == 0)
        atomicAdd(&acc[0], (double)(redn[0] + redn[1] + redn[2] + redn[3]));
    (void)c;
}

// ---------------------------------------------------------------------------
// fallback: round-2 all-in-one kernel (used only if ws too small for mask)
// ---------------------------------------------------------------------------
#define FBSTRIPH 256
#define FBNSUP (FBSTRIPH / SUP)
__global__ __launch_bounds__(256) void ssim_main_fb(
    const float* __restrict__ img1, const float* __restrict__ img2,
    const float* __restrict__ match, double* __restrict__ acc)
{
    __shared__ __align__(16) float ring1[RINGR][LDSW];
    __shared__ __align__(16) float ring2[RINGR][LDSW];
    __shared__ __align__(16) float ringm[RINGR][LDSW];
    __shared__ __align__(16) float fld[6][SUP][LDSW];
    __shared__ float redn[4], redd[4];

    const int tid = threadIdx.x;
    const int bc = blockIdx.z;
    const int b = bc / CHANS;
    const int c = bc - b * CHANS;
    const int ystart = blockIdx.y * FBSTRIPH;
    const int bx0 = blockIdx.x * STRIPW - 8;

    const float* p1 = img1 + (size_t)(b * CHANS + c) * (IMH * IMW);
    const float* p2 = img2 + (size_t)(b * CHANS + c) * (IMH * IMW);
    const float* pm = match + (size_t)b * (IMH * IMW);

    float g[11];
    {
        float s = 0.0f;
        #pragma unroll
        for (int i = 0; i < 11; ++i) {
            float d = (float)(i - 5);
            g[i] = expf(-(d * d) / 4.5f);
            s += g[i];
        }
        #pragma unroll
        for (int i = 0; i < 11; ++i) g[i] /= s;
    }

    float num = 0.0f, den = 0.0f;

    auto stage = [&](int gy0, int nrows) {
        for (int t = tid; t < nrows * NQ; t += 256) {
            int r = t / NQ, q = t - r * NQ;
            int gy = gy0 + r;
            int slot = (gy + 36) % RINGR;
            int gx = bx0 + 4 * q;
            float4 v1, v2, vm;
            if ((unsigned)gy < IMH && (unsigned)gx <= (IMW - 4)) {
                v1 = ld4s(p1 + gy * IMW + gx);
                v2 = ld4s(p2 + gy * IMW + gx);
                vm = ld4s(pm + gy * IMW + gx);
            } else if ((unsigned)gy < IMH) {
                float t1[4], t2[4], tm[4];
                #pragma unroll
                for (int e = 0; e < 4; ++e) {
                    int x = gx + e;
                    bool ok = (unsigned)x < IMW;
                    int off = gy * IMW + (ok ? x : 0);
                    t1[e] = ok ? p1[off] : 0.0f;
                    t2[e] = ok ? p2[off] : 0.0f;
                    tm[e] = ok ? pm[off] : 0.0f;
                }
                v1 = make_float4(t1[0], t1[1], t1[2], t1[3]);
                v2 = make_float4(t2[0], t2[1], t2[2], t2[3]);
                vm = make_float4(tm[0], tm[1], tm[2], tm[3]);
            } else {
                v1 = v2 = vm = make_float4(0.f, 0.f, 0.f, 0.f);
            }
            st4s(&ring1[slot][4 * q], v1);
            st4s(&ring2[slot][4 * q], v2);
            st4s(&ringm[slot][4 * q], vm);
        }
    };

    stage(ystart - 5, 10);

    for (int s = 0; s < FBNSUP; ++s) {
        const int ybase = ystart + s * SUP;
        stage(ybase + 5, SUP);
        __syncthreads();

        if (tid < SUP * NQ) {
            int r = tid / NQ, q = tid - r * NQ;
            int cq = 4 * q;
            int sr = (ybase + r + 31) % RINGR;
            float4 a1 = make_float4(0,0,0,0), a2 = a1, a3 = a1,
                   a4 = a1, a5 = a1, am = a1;
            #pragma unroll
            for (int k = 0; k < 11; ++k) {
                float4 x1 = ld4s(&ring1[sr][cq]);
                float4 x2 = ld4s(&ring2[sr][cq]);
                float4 xm = ld4s(&ringm[sr][cq]);
                float w = g[k];
                fma4(a1, w, x1);
                fma4(a2, w, x2);
                fma4m(a3, w, x1, x1);
                fma4m(a4, w, x2, x2);
                fma4m(a5, w, x1, x2);
                add4(am, xm);
                sr++; if (sr >= RINGR) sr -= RINGR;
            }
            st4s(&fld[0][r][cq], a1);
            st4s(&fld[1][r][cq], a2);
            st4s(&fld[2][r][cq], a3);
            st4s(&fld[3][r][cq], a4);
            st4s(&fld[4][r][cq], a5);
            st4s(&fld[5][r][cq], am);
        }
        __syncthreads();

        if (tid < SUP * 16) {
            int r = tid >> 4, q = tid & 15;
            int cb = 4 * q;
            float mu1[4], mu2[4], m11[4], m22[4], m12[4], mb[4];
            convg(fld[0][r], cb, g, mu1);
            convg(fld[1][r], cb, g, mu2);
            convg(fld[2][r], cb, g, m11);
            convg(fld[3][r], cb, g, m22);
            convg(fld[4][r], cb, g, m12);
            convb(fld[5][r], cb, mb);
            #pragma unroll
            for (int j = 0; j < 4; ++j) {
                float mu1s = mu1[j] * mu1[j];
                float mu2s = mu2[j] * mu2[j];
                float mu12 = mu1[j] * mu2[j];
                float sg1  = m11[j] - mu1s;
                float sg2  = m22[j] - mu2s;
                float sg12 = m12[j] - mu12;
                float ssim = ((2.0f * mu12 + 1e-4f) * (2.0f * sg12 + 9e-4f)) /
                             ((mu1s + mu2s + 1e-4f) * (sg1 + sg2 + 9e-4f));
                float m = mb[j] * (1.0f / 121.0f) + 1e-7f;
                float mask = (m > 0.5f) ? (1.0f + 1e-7f) : 1e-7f;
                num += (1.0f - ssim) * mask;
                den += mask;
            }
        }
    }

    for (int off = 32; off > 0; off >>= 1) {
        num += __shfl_down(num, off);
        den += __shfl_down(den, off);
    }
    int wave = tid >> 6;
    int lane = tid & 63;
    if (lane == 0) { redn[wave] = num; redd[wave] = den; }
    __syncthreads();
    if (tid == 0) {
        float n = redn[0] + redn[1] + redn[2] + redn[3];
        atomicAdd(&acc[0], (double)n);
        if (c == 0) {
            float d = redd[0] + redd[1] + redd[2] + redd[3];
            atomicAdd(&acc[1], (double)d);
        }
    }
}

__global__ void init_acc(double* acc, float* gw) {
    acc[0] = 0.0;
    acc[1] = 0.0;
    if (gw != nullptr) {
        // same expf sequence as the reference-matched in-kernel computation
        float t[11];
        float s = 0.0f;
        for (int i = 0; i < 11; ++i) {
            float d = (float)(i - 5);
            t[i] = expf(-(d * d) / 4.5f);
            s += t[i];
        }
        for (int i = 0; i < 11; ++i) gw[i] = t[i] / s;
    }
}

__global__ void finalize(const double* __restrict__ acc, float* __restrict__ out) {
    out[0] = (float)(acc[0] / acc[1] / 3.0);
}

extern "C" void kernel_launch(void* const* d_in, const int* in_sizes, int n_in,
                              void* d_out, int out_size, void* d_ws, size_t ws_size,
                              hipStream_t stream) {
    const float* img1  = (const float*)d_in[0];
    const float* img2  = (const float*)d_in[1];
    const float* match = (const float*)d_in[2];
    float* out = (float*)d_out;
    double* acc = (double*)d_ws;                       // 16 B @ ws+0

    const size_t mask_need = 128 + (size_t)BATCH * IMH * IMW;  // 4,194,432 B
    const bool premask = (ws_size >= mask_need);
    float* gw = premask ? (float*)((char*)d_ws + 64) : nullptr;  // 44 B @ ws+64

    init_acc<<<1, 1, 0, stream>>>(acc, gw);

    dim3 block(256, 1, 1);
    if (premask) {
        unsigned char* mbuf = (unsigned char*)d_ws + 128;
        dim3 mgrid(IMW / MTW, IMH / MTH, BATCH);               // 8 x 8 x 16
        mask_pass<<<mgrid, block, 0, stream>>>(match, mbuf, acc);
        dim3 grid(IMW / STRIPW, IMH / STRIPH, BATCH * CHANS);  // 8 x 8 x 48
        ssim_main_pm<<<grid, block, 0, stream>>>(img1, img2, mbuf, gw, acc);
    } else {
        dim3 grid(IMW / STRIPW, IMH / FBSTRIPH, BATCH * CHANS);
        ssim_main_fb<<<grid, block, 0, stream>>>(img1, img2, match, acc);
    }

    finalize<<<1, 1, 0, stream>>>(acc, out);
}

// Round 7
// 236.102 us; speedup vs baseline: 1.0949x; 1.0949x over previous
//
#include <hip/hip_runtime.h>

// SSIM_13443247637111 — fused separable SSIM, V-first ring-buffer design.
// B=16, CH=3, 512x512, 11x11 gaussian sigma 1.5, zero padding 5.
//
// Round-9 structure = Round-4 (116us proven: f4-V + f2-H, VGPR 60, no spill)
// + ONE change: V-phase thread mapping transposed for bank uniformity.
//  - ROUND-6 POST-MORTEM: convg4s H pushed VGPR past the (256,4) cap ->
//    11.7 MB scratch spills, 144us. Conflicts = exactly R3's 2.561e7 (same
//    H pattern) -> f4-H carries +0.8e7 conflicts vs f2-H; R4 is the
//    empirical conflict minimum. convg4s REVERTED; f2-H restored.
//  - V mapping r=tid/20 had 20-lane same-row groups: b128 start banks
//    collide (q, q+8, q+16 same bank; max load ~10 vs 8 ideal). New mapping
//    r=tid&7, q=tid>>3: each 8-lane group has r=0..7 -> start banks
//    {20r mod 32} = {0,20,8,28,16,4,24,12}, 8 distinct x 4 words = all 32
//    banks exactly once, for ring reads AND fld writes. Single-variable A/B
//    vs R4: same arithmetic per output, same global access pattern.
//  - Everything else frozen: premask design, 2 rings + 5 fld = 25.6 KB LDS,
//    __launch_bounds__(256,4), grid 8x8x48 = 3072 blocks.

#define BATCH 16
#define CHANS 3
#define IMH 512
#define IMW 512
#define STRIPW 64
#define STRIPH 64
#define RINGR 18            // raw rows resident: y-5 .. y+12 for an 8-row super
#define LDSW 84             // padded row width; col c <-> x = bx*64 + c - 8
#define SUP 8               // output rows per super-iteration
#define NSUP (STRIPH / SUP) // 8
#define NQ 20               // float4 quads per staged row (80 cols)

// mask-pass tile
#define MTW 64
#define MTH 64
#define MRAWH 74            // MTH + 10 halo rows

__device__ __forceinline__ float4 ld4s(const float* p) { return *(const float4*)p; }
__device__ __forceinline__ void st4s(float* p, float4 v) { *(float4*)p = v; }
__device__ __forceinline__ void fma4(float4& a, float w, float4 x) {
    a.x = fmaf(w, x.x, a.x); a.y = fmaf(w, x.y, a.y);
    a.z = fmaf(w, x.z, a.z); a.w = fmaf(w, x.w, a.w);
}
__device__ __forceinline__ void fma4m(float4& a, float w, float4 x, float4 y) {
    a.x = fmaf(w, x.x * y.x, a.x); a.y = fmaf(w, x.y * y.y, a.y);
    a.z = fmaf(w, x.z * y.z, a.z); a.w = fmaf(w, x.w * y.w, a.w);
}
__device__ __forceinline__ void add4(float4& a, float4 x) {
    a.x += x.x; a.y += x.y; a.z += x.z; a.w += x.w;
}

// classic 20-float-window forms (mask_pass / fallback kernel only)
__device__ __forceinline__ void convg(const float* __restrict__ row, int cb,
                                      const float* __restrict__ g, float out[4]) {
    float w[20];
    #pragma unroll
    for (int i = 0; i < 5; ++i) {
        float4 v = ld4s(row + cb + 4 * i);
        w[4*i+0] = v.x; w[4*i+1] = v.y; w[4*i+2] = v.z; w[4*i+3] = v.w;
    }
    #pragma unroll
    for (int j = 0; j < 4; ++j) {
        float a = 0.0f;
        #pragma unroll
        for (int k = 0; k < 11; ++k) a = fmaf(g[k], w[3 + j + k], a);
        out[j] = a;
    }
}

__device__ __forceinline__ void convb(const float* __restrict__ row, int cb,
                                      float out[4]) {
    float w[20];
    #pragma unroll
    for (int i = 0; i < 5; ++i) {
        float4 v = ld4s(row + cb + 4 * i);
        w[4*i+0] = v.x; w[4*i+1] = v.y; w[4*i+2] = v.z; w[4*i+3] = v.w;
    }
    #pragma unroll
    for (int j = 0; j < 4; ++j) {
        float a = 0.0f;
        #pragma unroll
        for (int k = 0; k < 11; ++k) a += w[3 + j + k];
        out[j] = a;
    }
}

// ---------------------------------------------------------------------------
// mask precompute: box-filter match (11x11), threshold, store uint8 per pixel.
// Also accumulates the full denominator sum(mask) into acc[1].
// ---------------------------------------------------------------------------
__global__ __launch_bounds__(256) void mask_pass(
    const float* __restrict__ match, unsigned char* __restrict__ maskbuf,
    double* __restrict__ acc)
{
    __shared__ __align__(16) float raw[MRAWH][LDSW];
    __shared__ __align__(16) float vs[MTH][LDSW];
    __shared__ float red[4];

    const int tid = threadIdx.x;
    const int b = blockIdx.z;
    const int x0 = blockIdx.x * MTW - 8;     // global x of LDS col 0 (aligned)
    const int y0 = blockIdx.y * MTH - 5;
    const float* pm = match + (size_t)b * (IMH * IMW);

    // stage 74 rows x 20 quads (cols x0 .. x0+79), zero pad OOB
    for (int t = tid; t < MRAWH * NQ; t += 256) {
        int r = t / NQ, q = t - r * NQ;
        int gy = y0 + r;
        int gx = x0 + 4 * q;
        float4 v = make_float4(0.f, 0.f, 0.f, 0.f);
        if ((unsigned)gy < IMH) {
            if ((unsigned)gx <= (IMW - 4)) {
                v = ld4s(pm + gy * IMW + gx);
            } else {
                float tmp[4];
                #pragma unroll
                for (int e = 0; e < 4; ++e) {
                    int x = gx + e;
                    bool ok = (unsigned)x < IMW;
                    tmp[e] = ok ? pm[gy * IMW + x] : 0.0f;
                }
                v = make_float4(tmp[0], tmp[1], tmp[2], tmp[3]);
            }
        }
        st4s(&raw[r][4 * q], v);
    }
    __syncthreads();

    // vertical box: 64 rows x 20 quads
    for (int t = tid; t < MTH * NQ; t += 256) {
        int r = t / NQ, q = t - r * NQ;
        int cq = 4 * q;
        float4 a = make_float4(0.f, 0.f, 0.f, 0.f);
        #pragma unroll
        for (int k = 0; k < 11; ++k) add4(a, ld4s(&raw[r + k][cq]));
        st4s(&vs[r][cq], a);
    }
    __syncthreads();

    // horizontal box + threshold: 64 rows x 16 quads
    float den = 0.0f;
    for (int t = tid; t < MTH * 16; t += 256) {
        int r = t >> 4, q = t & 15;
        float mb[4];
        convb(vs[r], 4 * q, mb);
        unsigned char bits[4];
        #pragma unroll
        for (int j = 0; j < 4; ++j) {
            float m = mb[j] * (1.0f / 121.0f) + 1e-7f;
            bool on = m > 0.5f;
            bits[j] = (unsigned char)on;
            den += on ? (1.0f + 1e-7f) : 1e-7f;
        }
        int gy = blockIdx.y * MTH + r;
        int gx = blockIdx.x * MTW + 4 * q;
        *(uchar4*)(maskbuf + ((size_t)b << 18) + (gy << 9) + gx) =
            make_uchar4(bits[0], bits[1], bits[2], bits[3]);
    }

    for (int off = 32; off > 0; off >>= 1) den += __shfl_down(den, off);
    if ((tid & 63) == 0) red[tid >> 6] = den;
    __syncthreads();
    if (tid == 0)
        atomicAdd(&acc[1], (double)(red[0] + red[1] + red[2] + red[3]));
}

// ---------------------------------------------------------------------------
// main SSIM kernel: 2 rings + 5 fld arrays, LDS 25.6 KB.
// V phase: 160 threads x float4, TRANSPOSED mapping (r=tid&7, q=tid>>3) for
// bank-uniform b128 access. H phase: 256 threads x float2 (round-4 proven).
// Grid 8x8x48 = 3072 blocks.
// ---------------------------------------------------------------------------
__global__ __launch_bounds__(256, 4) void ssim_main_pm(
    const float* __restrict__ img1, const float* __restrict__ img2,
    const unsigned char* __restrict__ maskbuf,
    const float* __restrict__ gw, double* __restrict__ acc)
{
    __shared__ __align__(16) float ring1[RINGR][LDSW];
    __shared__ __align__(16) float ring2[RINGR][LDSW];
    __shared__ __align__(16) float fld[5][SUP][LDSW];
    __shared__ float redn[4];

    const int tid = threadIdx.x;
    const int bc = blockIdx.z;
    const int b = bc / CHANS;
    const int c = bc - b * CHANS;
    const int ystart = blockIdx.y * STRIPH;
    const int bxg = blockIdx.x;
    const int bx0 = bxg * STRIPW - 8;   // global x of LDS col 0

    const float* p1 = img1 + (size_t)(b * CHANS + c) * (IMH * IMW);
    const float* p2 = img2 + (size_t)(b * CHANS + c) * (IMH * IMW);
    const unsigned char* pmk = maskbuf + ((size_t)b << 18);

    // weights: uniform pointer + constant offsets -> scalar loads (SGPRs),
    // bit-identical to the expf sequence the reference-matched kernels used.
    float g[11];
    #pragma unroll
    for (int i = 0; i < 11; ++i) g[i] = gw[i];

    float num = 0.0f;
    const bool colsafe = (bx0 >= 0) && (bx0 + 4 * NQ <= IMW);  // interior in x

    auto stage = [&](int gy0, int nrows) {
        // nrows*NQ <= 200 < 256: single shot, no loop
        if (tid < nrows * NQ) {
            int r = tid / NQ, q = tid - r * NQ;
            int gy = gy0 + r;
            int slot = (gy + 36) % RINGR;
            int gx = bx0 + 4 * q;
            float4 v1 = make_float4(0.f, 0.f, 0.f, 0.f), v2 = v1;
            if ((unsigned)gy < IMH) {
                if (colsafe || (unsigned)gx <= (IMW - 4)) {
                    v1 = ld4s(p1 + gy * IMW + gx);
                    v2 = ld4s(p2 + gy * IMW + gx);
                } else {
                    float t1[4], t2[4];
                    #pragma unroll
                    for (int e = 0; e < 4; ++e) {
                        int x = gx + e;
                        bool ok = (unsigned)x < IMW;
                        int off = gy * IMW + (ok ? x : 0);
                        t1[e] = ok ? p1[off] : 0.0f;
                        t2[e] = ok ? p2[off] : 0.0f;
                    }
                    v1 = make_float4(t1[0], t1[1], t1[2], t1[3]);
                    v2 = make_float4(t2[0], t2[1], t2[2], t2[3]);
                }
            }
            st4s(&ring1[slot][4 * q], v1);
            st4s(&ring2[slot][4 * q], v2);
        }
    };

    // prologue: raw rows ystart-5 .. ystart+4
    stage(ystart - 5, 10);

    for (int s = 0; s < NSUP; ++s) {
        const int ybase = ystart + s * SUP;

        // stage the 8 new raw rows this super needs (ybase+5 .. ybase+12).
        // safe: slots being overwritten were last read by V of super s-1,
        // which completed before barrier B2 of super s-1.
        stage(ybase + 5, SUP);
        __syncthreads();   // B1: staging visible; fld free (H of s-1 done)

        // ---- vertical pass: 8 rows x 20 quads, transposed mapping ----
        // r = tid&7, q = tid>>3: each 8-lane group spans r=0..7 at fixed q
        // -> b128 start banks {20r mod 32} all distinct -> 32 banks exactly
        // once per group (reads from ring AND writes to fld).
        if (tid < SUP * NQ) {
            int r = tid & 7, q = tid >> 3;
            int cq = 4 * q;
            int sr = (ybase + r + 31) % RINGR;   // row (y-5)
            float4 a1 = make_float4(0,0,0,0), a2 = a1, a3 = a1,
                   a4 = a1, a5 = a1;
            #pragma unroll
            for (int k = 0; k < 11; ++k) {
                float4 x1 = ld4s(&ring1[sr][cq]);
                float4 x2 = ld4s(&ring2[sr][cq]);
                float w = g[k];
                fma4(a1, w, x1);
                fma4(a2, w, x2);
                fma4m(a3, w, x1, x1);
                fma4m(a4, w, x2, x2);
                fma4m(a5, w, x1, x2);
                sr++; if (sr >= RINGR) sr -= RINGR;
            }
            st4s(&fld[0][r][cq], a1);
            st4s(&fld[1][r][cq], a2);
            st4s(&fld[2][r][cq], a3);
            st4s(&fld[3][r][cq], a4);
            st4s(&fld[4][r][cq], a5);
        }
        __syncthreads();   // B2: fld visible; ring free for next stage

        // ---- horizontal pass + SSIM: 8 rows x 32 float2 cols, 256 thr ----
        {
            int r = tid >> 5, h = tid & 31;
            // outputs at strip cols 2h, 2h+1 (LDS cols 2h+8, 2h+9).
            // taps for out0: LDS cols 2h+3 .. 2h+13; out1: 2h+4 .. 2h+14.
            // load LDS cols 2h+2 .. 2h+15 as 7 float2 (8B aligned, constant
            // in-register offsets -> no runtime-indexed array -> no scratch).
            const int c0 = 2 * h + 2;
            float mu1[2], mu2[2], m11[2], m22[2], m12[2];
            auto convg2 = [&](const float* __restrict__ row, float out[2]) {
                float wf[14];
                #pragma unroll
                for (int i = 0; i < 7; ++i) {
                    float2 v = *(const float2*)(row + c0 + 2 * i);
                    wf[2*i]   = v.x;
                    wf[2*i+1] = v.y;
                }
                float a0 = 0.0f, a1 = 0.0f;
                #pragma unroll
                for (int k = 0; k < 11; ++k) {
                    a0 = fmaf(g[k], wf[1 + k], a0);
                    a1 = fmaf(g[k], wf[2 + k], a1);
                }
                out[0] = a0; out[1] = a1;
            };
            convg2(fld[0][r], mu1);
            convg2(fld[1][r], mu2);
            convg2(fld[2][r], m11);
            convg2(fld[3][r], m22);
            convg2(fld[4][r], m12);

            int gy = ybase + r;
            int gx = bxg * STRIPW + 2 * h;
            uchar2 mk = *(const uchar2*)(pmk + (gy << 9) + gx);
            const unsigned char mkv[2] = {mk.x, mk.y};
            #pragma unroll
            for (int j = 0; j < 2; ++j) {
                float mu1s = mu1[j] * mu1[j];
                float mu2s = mu2[j] * mu2[j];
                float mu12 = mu1[j] * mu2[j];
                float sg1  = m11[j] - mu1s;
                float sg2  = m22[j] - mu2s;
                float sg12 = m12[j] - mu12;
                float ssim = ((2.0f * mu12 + 1e-4f) * (2.0f * sg12 + 9e-4f)) /
                             ((mu1s + mu2s + 1e-4f) * (sg1 + sg2 + 9e-4f));
                float mask = mkv[j] ? (1.0f + 1e-7f) : 1e-7f;
                num += (1.0f - ssim) * mask;
            }
        }
    }

    // ---- block reduction: wave shuffle (width 64) then cross-wave LDS ----
    for (int off = 32; off > 0; off >>= 1) num += __shfl_down(num, off);
    if ((tid & 63) == 0) redn[tid >> 6] = num;
    __syncthreads();
    if (tid == 0)
        atomicAdd(&acc[0], (double)(redn[0] + redn[1] + redn[2] + redn[3]));
    (void)c;
}

// ---------------------------------------------------------------------------
// fallback: round-2 all-in-one kernel (used only if ws too small for mask)
// ---------------------------------------------------------------------------
#define FBSTRIPH 256
#define FBNSUP (FBSTRIPH / SUP)
__global__ __launch_bounds__(256) void ssim_main_fb(
    const float* __restrict__ img1, const float* __restrict__ img2,
    const float* __restrict__ match, double* __restrict__ acc)
{
    __shared__ __align__(16) float ring1[RINGR][LDSW];
    __shared__ __align__(16) float ring2[RINGR][LDSW];
    __shared__ __align__(16) float ringm[RINGR][LDSW];
    __shared__ __align__(16) float fld[6][SUP][LDSW];
    __shared__ float redn[4], redd[4];

    const int tid = threadIdx.x;
    const int bc = blockIdx.z;
    const int b = bc / CHANS;
    const int c = bc - b * CHANS;
    const int ystart = blockIdx.y * FBSTRIPH;
    const int bx0 = blockIdx.x * STRIPW - 8;

    const float* p1 = img1 + (size_t)(b * CHANS + c) * (IMH * IMW);
    const float* p2 = img2 + (size_t)(b * CHANS + c) * (IMH * IMW);
    const float* pm = match + (size_t)b * (IMH * IMW);

    float g[11];
    {
        float s = 0.0f;
        #pragma unroll
        for (int i = 0; i < 11; ++i) {
            float d = (float)(i - 5);
            g[i] = expf(-(d * d) / 4.5f);
            s += g[i];
        }
        #pragma unroll
        for (int i = 0; i < 11; ++i) g[i] /= s;
    }

    float num = 0.0f, den = 0.0f;

    auto stage = [&](int gy0, int nrows) {
        for (int t = tid; t < nrows * NQ; t += 256) {
            int r = t / NQ, q = t - r * NQ;
            int gy = gy0 + r;
            int slot = (gy + 36) % RINGR;
            int gx = bx0 + 4 * q;
            float4 v1, v2, vm;
            if ((unsigned)gy < IMH && (unsigned)gx <= (IMW - 4)) {
                v1 = ld4s(p1 + gy * IMW + gx);
                v2 = ld4s(p2 + gy * IMW + gx);
                vm = ld4s(pm + gy * IMW + gx);
            } else if ((unsigned)gy < IMH) {
                float t1[4], t2[4], tm[4];
                #pragma unroll
                for (int e = 0; e < 4; ++e) {
                    int x = gx + e;
                    bool ok = (unsigned)x < IMW;
                    int off = gy * IMW + (ok ? x : 0);
                    t1[e] = ok ? p1[off] : 0.0f;
                    t2[e] = ok ? p2[off] : 0.0f;
                    tm[e] = ok ? pm[off] : 0.0f;
                }
                v1 = make_float4(t1[0], t1[1], t1[2], t1[3]);
                v2 = make_float4(t2[0], t2[1], t2[2], t2[3]);
                vm = make_float4(tm[0], tm[1], tm[2], tm[3]);
            } else {
                v1 = v2 = vm = make_float4(0.f, 0.f, 0.f, 0.f);
            }
            st4s(&ring1[slot][4 * q], v1);
            st4s(&ring2[slot][4 * q], v2);
            st4s(&ringm[slot][4 * q], vm);
        }
    };

    stage(ystart - 5, 10);

    for (int s = 0; s < FBNSUP; ++s) {
        const int ybase = ystart + s * SUP;
        stage(ybase + 5, SUP);
        __syncthreads();

        if (tid < SUP * NQ) {
            int r = tid / NQ, q = tid - r * NQ;
            int cq = 4 * q;
            int sr = (ybase + r + 31) % RINGR;
            float4 a1 = make_float4(0,0,0,0), a2 = a1, a3 = a1,
                   a4 = a1, a5 = a1, am = a1;
            #pragma unroll
            for (int k = 0; k < 11; ++k) {
                float4 x1 = ld4s(&ring1[sr][cq]);
                float4 x2 = ld4s(&ring2[sr][cq]);
                float4 xm = ld4s(&ringm[sr][cq]);
                float w = g[k];
                fma4(a1, w, x1);
                fma4(a2, w, x2);
                fma4m(a3, w, x1, x1);
                fma4m(a4, w, x2, x2);
                fma4m(a5, w, x1, x2);
                add4(am, xm);
                sr++; if (sr >= RINGR) sr -= RINGR;
            }
            st4s(&fld[0][r][cq], a1);
            st4s(&fld[1][r][cq], a2);
            st4s(&fld[2][r][cq], a3);
            st4s(&fld[3][r][cq], a4);
            st4s(&fld[4][r][cq], a5);
            st4s(&fld[5][r][cq], am);
        }
        __syncthreads();

        if (tid < SUP * 16) {
            int r = tid >> 4, q = tid & 15;
            int cb = 4 * q;
            float mu1[4], mu2[4], m11[4], m22[4], m12[4], mb[4];
            convg(fld[0][r], cb, g, mu1);
            convg(fld[1][r], cb, g, mu2);
            convg(fld[2][r], cb, g, m11);
            convg(fld[3][r], cb, g, m22);
            convg(fld[4][r], cb, g, m12);
            convb(fld[5][r], cb, mb);
            #pragma unroll
            for (int j = 0; j < 4; ++j) {
                float mu1s = mu1[j] * mu1[j];
                float mu2s = mu2[j] * mu2[j];
                float mu12 = mu1[j] * mu2[j];
                float sg1  = m11[j] - mu1s;
                float sg2  = m22[j] - mu2s;
                float sg12 = m12[j] - mu12;
                float ssim = ((2.0f * mu12 + 1e-4f) * (2.0f * sg12 + 9e-4f)) /
                             ((mu1s + mu2s + 1e-4f) * (sg1 + sg2 + 9e-4f));
                float m = mb[j] * (1.0f / 121.0f) + 1e-7f;
                float mask = (m > 0.5f) ? (1.0f + 1e-7f) : 1e-7f;
                num += (1.0f - ssim) * mask;
                den += mask;
            }
        }
    }

    for (int off = 32; off > 0; off >>= 1) {
        num += __shfl_down(num, off);
        den += __shfl_down(den, off);
    }
    int wave = tid >> 6;
    int lane = tid & 63;
    if (lane == 0) { redn[wave] = num; redd[wave] = den; }
    __syncthreads();
    if (tid == 0) {
        float n = redn[0] + redn[1] + redn[2] + redn[3];
        atomicAdd(&acc[0], (double)n);
        if (c == 0) {
            float d = redd[0] + redd[1] + redd[2] + redd[3];
            atomicAdd(&acc[1], (double)d);
        }
    }
}

__global__ void init_acc(double* acc, float* gw) {
    acc[0] = 0.0;
    acc[1] = 0.0;
    if (gw != nullptr) {
        // same expf sequence as the reference-matched in-kernel computation
        float t[11];
        float s = 0.0f;
        for (int i = 0; i < 11; ++i) {
            float d = (float)(i - 5);
            t[i] = expf(-(d * d) / 4.5f);
            s += t[i];
        }
        for (int i = 0; i < 11; ++i) gw[i] = t[i] / s;
    }
}

__global__ void finalize(const double* __restrict__ acc, float* __restrict__ out) {
    out[0] = (float)(acc[0] / acc[1] / 3.0);
}

extern "C" void kernel_launch(void* const* d_in, const int* in_sizes, int n_in,
                              void* d_out, int out_size, void* d_ws, size_t ws_size,
                              hipStream_t stream) {
    const float* img1  = (const float*)d_in[0];
    const float* img2  = (const float*)d_in[1];
    const float* match = (const float*)d_in[2];
    float* out = (float*)d_out;
    double* acc = (double*)d_ws;                       // 16 B @ ws+0

    const size_t mask_need = 128 + (size_t)BATCH * IMH * IMW;  // 4,194,432 B
    const bool premask = (ws_size >= mask_need);
    float* gw = premask ? (float*)((char*)d_ws + 64) : nullptr;  // 44 B @ ws+64

    init_acc<<<1, 1, 0, stream>>>(acc, gw);

    dim3 block(256, 1, 1);
    if (premask) {
        unsigned char* mbuf = (unsigned char*)d_ws + 128;
        dim3 mgrid(IMW / MTW, IMH / MTH, BATCH);               // 8 x 8 x 16
        mask_pass<<<mgrid, block, 0, stream>>>(match, mbuf, acc);
        dim3 grid(IMW / STRIPW, IMH / STRIPH, BATCH * CHANS);  // 8 x 8 x 48
        ssim_main_pm<<<grid, block, 0, stream>>>(img1, img2, mbuf, gw, acc);
    } else {
        dim3 grid(IMW / STRIPW, IMH / FBSTRIPH, BATCH * CHANS);
        ssim_main_fb<<<grid, block, 0, stream>>>(img1, img2, match, acc);
    }

    finalize<<<1, 1, 0, stream>>>(acc, out);
}

// Round 8
// 217.975 us; speedup vs baseline: 1.1860x; 1.0832x over previous
//
#include <hip/hip_runtime.h>

// SSIM_13443247637111 — fused separable SSIM, V-first ring-buffer design.
// B=16, CH=3, 512x512, 11x11 gaussian sigma 1.5, zero padding 5.
//
// Round-10 structure (f2V + f2H-streaming + 5 waves/SIMD + launch trim):
//  - ROUND-7 POST-MORTEM: V-transpose mapping REGRESSED (116->122.6us,
//    conflicts 1.73->2.18e7). Third failed analytic bank prediction ->
//    bank models abandoned; empirical A/B only. Cross-round additive
//    decomposition: H-f4-window = +0.84e7 conflicts vs H-f2; V-f2 = -0.23e7
//    vs V-f4 (R5 misattribution corrected by R6). Predicted minimum config:
//    f2-V + f2-H ~= 1.50e7.
//  - V phase: R5's proven f2 code (320 units / 256 thr). H phase: f2
//    STREAMING (same 7 float2 loads/addresses as R4-H -> conflict-neutral;
//    ascending-k per output -> bit-identical; live set wf[14] -> 2).
//  - Both phases small live sets -> __launch_bounds__(256,5): VGPR cap ~48
//    -> 5 waves/SIMD (occupancy model floor(256/VGPR), verified R1/R4/R7).
//    Spill canary: WRITE_SIZE must stay ~96 B.
//  - Launch trim: init_acc kernel replaced by hipMemsetAsync (capturable);
//    gaussian weights written by one thread of mask_pass. 4 -> 3 launches.
//  - Frozen: premask design, 2 rings + 5 fld = 25.6 KB LDS, stage mapping,
//    grid 8x8x48 = 3072 blocks.

#define BATCH 16
#define CHANS 3
#define IMH 512
#define IMW 512
#define STRIPW 64
#define STRIPH 64
#define RINGR 18            // raw rows resident: y-5 .. y+12 for an 8-row super
#define LDSW 84             // padded row width; col c <-> x = bx*64 + c - 8
#define SUP 8               // output rows per super-iteration
#define NSUP (STRIPH / SUP) // 8
#define NQ 20               // float4 quads per staged row (80 cols)

// mask-pass tile
#define MTW 64
#define MTH 64
#define MRAWH 74            // MTH + 10 halo rows

__device__ __forceinline__ float4 ld4s(const float* p) { return *(const float4*)p; }
__device__ __forceinline__ void st4s(float* p, float4 v) { *(float4*)p = v; }
__device__ __forceinline__ void fma4(float4& a, float w, float4 x) {
    a.x = fmaf(w, x.x, a.x); a.y = fmaf(w, x.y, a.y);
    a.z = fmaf(w, x.z, a.z); a.w = fmaf(w, x.w, a.w);
}
__device__ __forceinline__ void fma4m(float4& a, float w, float4 x, float4 y) {
    a.x = fmaf(w, x.x * y.x, a.x); a.y = fmaf(w, x.y * y.y, a.y);
    a.z = fmaf(w, x.z * y.z, a.z); a.w = fmaf(w, x.w * y.w, a.w);
}
__device__ __forceinline__ void add4(float4& a, float4 x) {
    a.x += x.x; a.y += x.y; a.z += x.z; a.w += x.w;
}

// classic 20-float-window forms (mask_pass / fallback kernel only)
__device__ __forceinline__ void convg(const float* __restrict__ row, int cb,
                                      const float* __restrict__ g, float out[4]) {
    float w[20];
    #pragma unroll
    for (int i = 0; i < 5; ++i) {
        float4 v = ld4s(row + cb + 4 * i);
        w[4*i+0] = v.x; w[4*i+1] = v.y; w[4*i+2] = v.z; w[4*i+3] = v.w;
    }
    #pragma unroll
    for (int j = 0; j < 4; ++j) {
        float a = 0.0f;
        #pragma unroll
        for (int k = 0; k < 11; ++k) a = fmaf(g[k], w[3 + j + k], a);
        out[j] = a;
    }
}

__device__ __forceinline__ void convb(const float* __restrict__ row, int cb,
                                      float out[4]) {
    float w[20];
    #pragma unroll
    for (int i = 0; i < 5; ++i) {
        float4 v = ld4s(row + cb + 4 * i);
        w[4*i+0] = v.x; w[4*i+1] = v.y; w[4*i+2] = v.z; w[4*i+3] = v.w;
    }
    #pragma unroll
    for (int j = 0; j < 4; ++j) {
        float a = 0.0f;
        #pragma unroll
        for (int k = 0; k < 11; ++k) a += w[3 + j + k];
        out[j] = a;
    }
}

// ---------------------------------------------------------------------------
// mask precompute: box-filter match (11x11), threshold, store uint8 per pixel.
// Accumulates the full denominator sum(mask) into acc[1]; block (0,0,0)
// also writes the gaussian weight table (same expf sequence as the
// reference-matched kernels -> bit-identical values).
// ---------------------------------------------------------------------------
__global__ __launch_bounds__(256) void mask_pass(
    const float* __restrict__ match, unsigned char* __restrict__ maskbuf,
    float* __restrict__ gw, double* __restrict__ acc)
{
    __shared__ __align__(16) float raw[MRAWH][LDSW];
    __shared__ __align__(16) float vs[MTH][LDSW];
    __shared__ float red[4];

    const int tid = threadIdx.x;
    const int b = blockIdx.z;
    const int x0 = blockIdx.x * MTW - 8;     // global x of LDS col 0 (aligned)
    const int y0 = blockIdx.y * MTH - 5;
    const float* pm = match + (size_t)b * (IMH * IMW);

    // one thread of one block writes the weight table (read only by the
    // LATER ssim_main_pm launch -> stream-order safe)
    if (tid == 0 && blockIdx.x == 0 && blockIdx.y == 0 && b == 0) {
        float t[11];
        float s = 0.0f;
        for (int i = 0; i < 11; ++i) {
            float d = (float)(i - 5);
            t[i] = expf(-(d * d) / 4.5f);
            s += t[i];
        }
        for (int i = 0; i < 11; ++i) gw[i] = t[i] / s;
    }

    // stage 74 rows x 20 quads (cols x0 .. x0+79), zero pad OOB
    for (int t = tid; t < MRAWH * NQ; t += 256) {
        int r = t / NQ, q = t - r * NQ;
        int gy = y0 + r;
        int gx = x0 + 4 * q;
        float4 v = make_float4(0.f, 0.f, 0.f, 0.f);
        if ((unsigned)gy < IMH) {
            if ((unsigned)gx <= (IMW - 4)) {
                v = ld4s(pm + gy * IMW + gx);
            } else {
                float tmp[4];
                #pragma unroll
                for (int e = 0; e < 4; ++e) {
                    int x = gx + e;
                    bool ok = (unsigned)x < IMW;
                    tmp[e] = ok ? pm[gy * IMW + x] : 0.0f;
                }
                v = make_float4(tmp[0], tmp[1], tmp[2], tmp[3]);
            }
        }
        st4s(&raw[r][4 * q], v);
    }
    __syncthreads();

    // vertical box: 64 rows x 20 quads
    for (int t = tid; t < MTH * NQ; t += 256) {
        int r = t / NQ, q = t - r * NQ;
        int cq = 4 * q;
        float4 a = make_float4(0.f, 0.f, 0.f, 0.f);
        #pragma unroll
        for (int k = 0; k < 11; ++k) add4(a, ld4s(&raw[r + k][cq]));
        st4s(&vs[r][cq], a);
    }
    __syncthreads();

    // horizontal box + threshold: 64 rows x 16 quads
    float den = 0.0f;
    for (int t = tid; t < MTH * 16; t += 256) {
        int r = t >> 4, q = t & 15;
        float mb[4];
        convb(vs[r], 4 * q, mb);
        unsigned char bits[4];
        #pragma unroll
        for (int j = 0; j < 4; ++j) {
            float m = mb[j] * (1.0f / 121.0f) + 1e-7f;
            bool on = m > 0.5f;
            bits[j] = (unsigned char)on;
            den += on ? (1.0f + 1e-7f) : 1e-7f;
        }
        int gy = blockIdx.y * MTH + r;
        int gx = blockIdx.x * MTW + 4 * q;
        *(uchar4*)(maskbuf + ((size_t)b << 18) + (gy << 9) + gx) =
            make_uchar4(bits[0], bits[1], bits[2], bits[3]);
    }

    for (int off = 32; off > 0; off >>= 1) den += __shfl_down(den, off);
    if ((tid & 63) == 0) red[tid >> 6] = den;
    __syncthreads();
    if (tid == 0)
        atomicAdd(&acc[1], (double)(red[0] + red[1] + red[2] + red[3]));
}

// ---------------------------------------------------------------------------
// main SSIM kernel: 2 rings + 5 fld arrays, LDS 25.6 KB.
// V phase: f2 over 320 units (R5-proven). H phase: f2 streaming.
// __launch_bounds__(256,5): target 5 waves/SIMD. Grid 8x8x48 = 3072.
// ---------------------------------------------------------------------------
__global__ __launch_bounds__(256, 5) void ssim_main_pm(
    const float* __restrict__ img1, const float* __restrict__ img2,
    const unsigned char* __restrict__ maskbuf,
    const float* __restrict__ gw, double* __restrict__ acc)
{
    __shared__ __align__(16) float ring1[RINGR][LDSW];
    __shared__ __align__(16) float ring2[RINGR][LDSW];
    __shared__ __align__(16) float fld[5][SUP][LDSW];
    __shared__ float redn[4];

    const int tid = threadIdx.x;
    const int bc = blockIdx.z;
    const int b = bc / CHANS;
    const int c = bc - b * CHANS;
    const int ystart = blockIdx.y * STRIPH;
    const int bxg = blockIdx.x;
    const int bx0 = bxg * STRIPW - 8;   // global x of LDS col 0

    const float* p1 = img1 + (size_t)(b * CHANS + c) * (IMH * IMW);
    const float* p2 = img2 + (size_t)(b * CHANS + c) * (IMH * IMW);
    const unsigned char* pmk = maskbuf + ((size_t)b << 18);

    // weights: uniform pointer + constant offsets -> scalar loads (SGPRs)
    float g[11];
    #pragma unroll
    for (int i = 0; i < 11; ++i) g[i] = gw[i];

    float num = 0.0f;
    const bool colsafe = (bx0 >= 0) && (bx0 + 4 * NQ <= IMW);  // interior in x

    auto stage = [&](int gy0, int nrows) {
        // nrows*NQ <= 200 < 256: single shot, no loop
        if (tid < nrows * NQ) {
            int r = tid / NQ, q = tid - r * NQ;
            int gy = gy0 + r;
            int slot = (gy + 36) % RINGR;
            int gx = bx0 + 4 * q;
            float4 v1 = make_float4(0.f, 0.f, 0.f, 0.f), v2 = v1;
            if ((unsigned)gy < IMH) {
                if (colsafe || (unsigned)gx <= (IMW - 4)) {
                    v1 = ld4s(p1 + gy * IMW + gx);
                    v2 = ld4s(p2 + gy * IMW + gx);
                } else {
                    float t1[4], t2[4];
                    #pragma unroll
                    for (int e = 0; e < 4; ++e) {
                        int x = gx + e;
                        bool ok = (unsigned)x < IMW;
                        int off = gy * IMW + (ok ? x : 0);
                        t1[e] = ok ? p1[off] : 0.0f;
                        t2[e] = ok ? p2[off] : 0.0f;
                    }
                    v1 = make_float4(t1[0], t1[1], t1[2], t1[3]);
                    v2 = make_float4(t2[0], t2[1], t2[2], t2[3]);
                }
            }
            st4s(&ring1[slot][4 * q], v1);
            st4s(&ring2[slot][4 * q], v2);
        }
    };

    // prologue: raw rows ystart-5 .. ystart+4
    stage(ystart - 5, 10);

    for (int s = 0; s < NSUP; ++s) {
        const int ybase = ystart + s * SUP;

        // stage the 8 new raw rows this super needs (ybase+5 .. ybase+12).
        stage(ybase + 5, SUP);
        __syncthreads();   // B1: staging visible; fld free (H of s-1 done)

        // ---- vertical pass: 320 float2 units over 256 threads (R5 code) ----
        // unit u -> row r = u/40, half-quad hq = u%40 (cols 2hq, 2hq+1).
        #pragma unroll
        for (int pass = 0; pass < 2; ++pass) {
            if (pass == 0 || tid < SUP * 40 - 256) {   // pass1: 64 threads
                const int u = tid + pass * 256;
                const int r = u / 40, hq = u - r * 40;
                const int cw = 2 * hq;
                int sr = (ybase + r + 31) % RINGR;     // row (y-5)
                float2 a1 = make_float2(0.f, 0.f), a2 = a1, a3 = a1,
                       a4 = a1, a5 = a1;
                #pragma unroll
                for (int k = 0; k < 11; ++k) {
                    float2 x1 = *(const float2*)&ring1[sr][cw];
                    float2 x2 = *(const float2*)&ring2[sr][cw];
                    float w = g[k];
                    a1.x = fmaf(w, x1.x, a1.x);        a1.y = fmaf(w, x1.y, a1.y);
                    a2.x = fmaf(w, x2.x, a2.x);        a2.y = fmaf(w, x2.y, a2.y);
                    a3.x = fmaf(w, x1.x * x1.x, a3.x); a3.y = fmaf(w, x1.y * x1.y, a3.y);
                    a4.x = fmaf(w, x2.x * x2.x, a4.x); a4.y = fmaf(w, x2.y * x2.y, a4.y);
                    a5.x = fmaf(w, x1.x * x2.x, a5.x); a5.y = fmaf(w, x1.y * x2.y, a5.y);
                    sr++; if (sr >= RINGR) sr -= RINGR;
                }
                *(float2*)&fld[0][r][cw] = a1;
                *(float2*)&fld[1][r][cw] = a2;
                *(float2*)&fld[2][r][cw] = a3;
                *(float2*)&fld[3][r][cw] = a4;
                *(float2*)&fld[4][r][cw] = a5;
            }
        }
        __syncthreads();   // B2: fld visible; ring free for next stage

        // ---- horizontal pass + SSIM: 8 rows x 32 float2 cols, 256 thr ----
        // STREAMING form: same 7 float2 loads at the same addresses as the
        // R4 wf[14] version (conflict-neutral), contributions applied in
        // ascending-k order per output -> bit-identical results; live set
        // drops from 14 window regs to 2.
        {
            int r = tid >> 5, h = tid & 31;
            const int c0 = 2 * h + 2;   // loads cols c0 .. c0+13
            float mu1[2], mu2[2], m11[2], m22[2], m12[2];
            auto convg2s = [&](const float* __restrict__ row, float out[2]) {
                float a0 = 0.0f, a1 = 0.0f;
                #pragma unroll
                for (int i = 0; i < 7; ++i) {
                    float2 v = *(const float2*)(row + c0 + 2 * i);
                    // out0 taps: cols c0+1..c0+11 (k = j-1, j = col-c0)
                    // out1 taps: cols c0+2..c0+12 (k = j-2)
                    if (i >= 1 && i <= 5) a0 = fmaf(g[2*i-1], v.x, a0);
                    if (i <= 5)           a0 = fmaf(g[2*i],   v.y, a0);
                    if (i >= 1)           a1 = fmaf(g[2*i-2], v.x, a1);
                    if (i >= 1 && i <= 5) a1 = fmaf(g[2*i-1], v.y, a1);
                }
                out[0] = a0; out[1] = a1;
            };
            convg2s(fld[0][r], mu1);
            convg2s(fld[1][r], mu2);
            convg2s(fld[2][r], m11);
            convg2s(fld[3][r], m22);
            convg2s(fld[4][r], m12);

            int gy = ybase + r;
            int gx = bxg * STRIPW + 2 * h;
            uchar2 mk = *(const uchar2*)(pmk + (gy << 9) + gx);
            const unsigned char mkv[2] = {mk.x, mk.y};
            #pragma unroll
            for (int j = 0; j < 2; ++j) {
                float mu1s = mu1[j] * mu1[j];
                float mu2s = mu2[j] * mu2[j];
                float mu12 = mu1[j] * mu2[j];
                float sg1  = m11[j] - mu1s;
                float sg2  = m22[j] - mu2s;
                float sg12 = m12[j] - mu12;
                float ssim = ((2.0f * mu12 + 1e-4f) * (2.0f * sg12 + 9e-4f)) /
                             ((mu1s + mu2s + 1e-4f) * (sg1 + sg2 + 9e-4f));
                float mask = mkv[j] ? (1.0f + 1e-7f) : 1e-7f;
                num += (1.0f - ssim) * mask;
            }
        }
    }

    // ---- block reduction: wave shuffle (width 64) then cross-wave LDS ----
    for (int off = 32; off > 0; off >>= 1) num += __shfl_down(num, off);
    if ((tid & 63) == 0) redn[tid >> 6] = num;
    __syncthreads();
    if (tid == 0)
        atomicAdd(&acc[0], (double)(redn[0] + redn[1] + redn[2] + redn[3]));
    (void)c;
}

// ---------------------------------------------------------------------------
// fallback: round-2 all-in-one kernel (used only if ws too small for mask)
// ---------------------------------------------------------------------------
#define FBSTRIPH 256
#define FBNSUP (FBSTRIPH / SUP)
__global__ __launch_bounds__(256) void ssim_main_fb(
    const float* __restrict__ img1, const float* __restrict__ img2,
    const float* __restrict__ match, double* __restrict__ acc)
{
    __shared__ __align__(16) float ring1[RINGR][LDSW];
    __shared__ __align__(16) float ring2[RINGR][LDSW];
    __shared__ __align__(16) float ringm[RINGR][LDSW];
    __shared__ __align__(16) float fld[6][SUP][LDSW];
    __shared__ float redn[4], redd[4];

    const int tid = threadIdx.x;
    const int bc = blockIdx.z;
    const int b = bc / CHANS;
    const int c = bc - b * CHANS;
    const int ystart = blockIdx.y * FBSTRIPH;
    const int bx0 = blockIdx.x * STRIPW - 8;

    const float* p1 = img1 + (size_t)(b * CHANS + c) * (IMH * IMW);
    const float* p2 = img2 + (size_t)(b * CHANS + c) * (IMH * IMW);
    const float* pm = match + (size_t)b * (IMH * IMW);

    float g[11];
    {
        float s = 0.0f;
        #pragma unroll
        for (int i = 0; i < 11; ++i) {
            float d = (float)(i - 5);
            g[i] = expf(-(d * d) / 4.5f);
            s += g[i];
        }
        #pragma unroll
        for (int i = 0; i < 11; ++i) g[i] /= s;
    }

    float num = 0.0f, den = 0.0f;

    auto stage = [&](int gy0, int nrows) {
        for (int t = tid; t < nrows * NQ; t += 256) {
            int r = t / NQ, q = t - r * NQ;
            int gy = gy0 + r;
            int slot = (gy + 36) % RINGR;
            int gx = bx0 + 4 * q;
            float4 v1, v2, vm;
            if ((unsigned)gy < IMH && (unsigned)gx <= (IMW - 4)) {
                v1 = ld4s(p1 + gy * IMW + gx);
                v2 = ld4s(p2 + gy * IMW + gx);
                vm = ld4s(pm + gy * IMW + gx);
            } else if ((unsigned)gy < IMH) {
                float t1[4], t2[4], tm[4];
                #pragma unroll
                for (int e = 0; e < 4; ++e) {
                    int x = gx + e;
                    bool ok = (unsigned)x < IMW;
                    int off = gy * IMW + (ok ? x : 0);
                    t1[e] = ok ? p1[off] : 0.0f;
                    t2[e] = ok ? p2[off] : 0.0f;
                    tm[e] = ok ? pm[off] : 0.0f;
                }
                v1 = make_float4(t1[0], t1[1], t1[2], t1[3]);
                v2 = make_float4(t2[0], t2[1], t2[2], t2[3]);
                vm = make_float4(tm[0], tm[1], tm[2], tm[3]);
            } else {
                v1 = v2 = vm = make_float4(0.f, 0.f, 0.f, 0.f);
            }
            st4s(&ring1[slot][4 * q], v1);
            st4s(&ring2[slot][4 * q], v2);
            st4s(&ringm[slot][4 * q], vm);
        }
    };

    stage(ystart - 5, 10);

    for (int s = 0; s < FBNSUP; ++s) {
        const int ybase = ystart + s * SUP;
        stage(ybase + 5, SUP);
        __syncthreads();

        if (tid < SUP * NQ) {
            int r = tid / NQ, q = tid - r * NQ;
            int cq = 4 * q;
            int sr = (ybase + r + 31) % RINGR;
            float4 a1 = make_float4(0,0,0,0), a2 = a1, a3 = a1,
                   a4 = a1, a5 = a1, am = a1;
            #pragma unroll
            for (int k = 0; k < 11; ++k) {
                float4 x1 = ld4s(&ring1[sr][cq]);
                float4 x2 = ld4s(&ring2[sr][cq]);
                float4 xm = ld4s(&ringm[sr][cq]);
                float w = g[k];
                fma4(a1, w, x1);
                fma4(a2, w, x2);
                fma4m(a3, w, x1, x1);
                fma4m(a4, w, x2, x2);
                fma4m(a5, w, x1, x2);
                add4(am, xm);
                sr++; if (sr >= RINGR) sr -= RINGR;
            }
            st4s(&fld[0][r][cq], a1);
            st4s(&fld[1][r][cq], a2);
            st4s(&fld[2][r][cq], a3);
            st4s(&fld[3][r][cq], a4);
            st4s(&fld[4][r][cq], a5);
            st4s(&fld[5][r][cq], am);
        }
        __syncthreads();

        if (tid < SUP * 16) {
            int r = tid >> 4, q = tid & 15;
            int cb = 4 * q;
            float mu1[4], mu2[4], m11[4], m22[4], m12[4], mb[4];
            convg(fld[0][r], cb, g, mu1);
            convg(fld[1][r], cb, g, mu2);
            convg(fld[2][r], cb, g, m11);
            convg(fld[3][r], cb, g, m22);
            convg(fld[4][r], cb, g, m12);
            convb(fld[5][r], cb, mb);
            #pragma unroll
            for (int j = 0; j < 4; ++j) {
                float mu1s = mu1[j] * mu1[j];
                float mu2s = mu2[j] * mu2[j];
                float mu12 = mu1[j] * mu2[j];
                float sg1  = m11[j] - mu1s;
                float sg2  = m22[j] - mu2s;
                float sg12 = m12[j] - mu12;
                float ssim = ((2.0f * mu12 + 1e-4f) * (2.0f * sg12 + 9e-4f)) /
                             ((mu1s + mu2s + 1e-4f) * (sg1 + sg2 + 9e-4f));
                float m = mb[j] * (1.0f / 121.0f) + 1e-7f;
                float mask = (m > 0.5f) ? (1.0f + 1e-7f) : 1e-7f;
                num += (1.0f - ssim) * mask;
                den += mask;
            }
        }
    }

    for (int off = 32; off > 0; off >>= 1) {
        num += __shfl_down(num, off);
        den += __shfl_down(den, off);
    }
    int wave = tid >> 6;
    int lane = tid & 63;
    if (lane == 0) { redn[wave] = num; redd[wave] = den; }
    __syncthreads();
    if (tid == 0) {
        float n = redn[0] + redn[1] + redn[2] + redn[3];
        atomicAdd(&acc[0], (double)n);
        if (c == 0) {
            float d = redd[0] + redd[1] + redd[2] + redd[3];
            atomicAdd(&acc[1], (double)d);
        }
    }
}

__global__ void finalize(const double* __restrict__ acc, float* __restrict__ out) {
    out[0] = (float)(acc[0] / acc[1] / 3.0);
}

extern "C" void kernel_launch(void* const* d_in, const int* in_sizes, int n_in,
                              void* d_out, int out_size, void* d_ws, size_t ws_size,
                              hipStream_t stream) {
    const float* img1  = (const float*)d_in[0];
    const float* img2  = (const float*)d_in[1];
    const float* match = (const float*)d_in[2];
    float* out = (float*)d_out;
    double* acc = (double*)d_ws;                       // 16 B @ ws+0

    const size_t mask_need = 128 + (size_t)BATCH * IMH * IMW;  // 4,194,432 B
    const bool premask = (ws_size >= mask_need);
    float* gw = (float*)((char*)d_ws + 64);            // 44 B @ ws+64

    // zero acc[0..1] (doubles: all-zero bytes == +0.0); capturable async op
    hipMemsetAsync(d_ws, 0, 16, stream);

    dim3 block(256, 1, 1);
    if (premask) {
        unsigned char* mbuf = (unsigned char*)d_ws + 128;
        dim3 mgrid(IMW / MTW, IMH / MTH, BATCH);               // 8 x 8 x 16
        mask_pass<<<mgrid, block, 0, stream>>>(match, mbuf, gw, acc);
        dim3 grid(IMW / STRIPW, IMH / STRIPH, BATCH * CHANS);  // 8 x 8 x 48
        ssim_main_pm<<<grid, block, 0, stream>>>(img1, img2, mbuf, gw, acc);
    } else {
        dim3 grid(IMW / STRIPW, IMH / FBSTRIPH, BATCH * CHANS);
        ssim_main_fb<<<grid, block, 0, stream>>>(img1, img2, match, acc);
    }

    finalize<<<1, 1, 0, stream>>>(acc, out);
}

// Round 9
// 215.985 us; speedup vs baseline: 1.1969x; 1.0092x over previous
//
#include <hip/hip_runtime.h>

// SSIM_13443247637111 — fused separable SSIM, V-first ring-buffer design.
// B=16, CH=3, 512x512, 11x11 gaussian sigma 1.5, zero padding 5.
//
// Round-11 structure (4-field algebraic reduction):
//  - ROUND-8 POST-MORTEM: all predictions hit (conflicts 1.497e7 vs
//    predicted 1.50e7; VGPR 40 no-spill; occ 55%; 111us). Kernel is now
//    approaching VALU-bound (67% busy) -> remove arithmetic, not rearrange.
//  - ALGEBRAIC CUT: SSIM uses sigma1_sq+sigma2_sq only as a SUM. Convolve
//    S = x1^2+x2^2 and P = x1*x2 instead of the three separate product
//    fields: 4 convolutions (A=conv x1, B=conv x2, S, P) instead of 5.
//      sgsum = hS - mu1^2 - mu2^2   (== sigma1_sq + sigma2_sq)
//      sg12  = hP - mu1*mu2         (== sigma12)
//    V: 8->7 VALU/elem/tap; fld writes 5->4; H: 55->44 fmaf and 35->28
//    LDS f2 reads per thread (-20% H VALU and H conflicts). LDS 22.9 KB.
//    NOT bit-identical (ulp-level reassociation) but output is one scalar
//    through double atomics -> float; per-pixel ulp noise vanishes.
//  - Everything else frozen from R8: f2-V (320 units), f2-H streaming,
//    __launch_bounds__(256,5), premask, memset-init, grid 8x8x48 = 3072.

#define BATCH 16
#define CHANS 3
#define IMH 512
#define IMW 512
#define STRIPW 64
#define STRIPH 64
#define RINGR 18            // raw rows resident: y-5 .. y+12 for an 8-row super
#define LDSW 84             // padded row width; col c <-> x = bx*64 + c - 8
#define SUP 8               // output rows per super-iteration
#define NSUP (STRIPH / SUP) // 8
#define NQ 20               // float4 quads per staged row (80 cols)

// mask-pass tile
#define MTW 64
#define MTH 64
#define MRAWH 74            // MTH + 10 halo rows

__device__ __forceinline__ float4 ld4s(const float* p) { return *(const float4*)p; }
__device__ __forceinline__ void st4s(float* p, float4 v) { *(float4*)p = v; }
__device__ __forceinline__ void fma4(float4& a, float w, float4 x) {
    a.x = fmaf(w, x.x, a.x); a.y = fmaf(w, x.y, a.y);
    a.z = fmaf(w, x.z, a.z); a.w = fmaf(w, x.w, a.w);
}
__device__ __forceinline__ void fma4m(float4& a, float w, float4 x, float4 y) {
    a.x = fmaf(w, x.x * y.x, a.x); a.y = fmaf(w, x.y * y.y, a.y);
    a.z = fmaf(w, x.z * y.z, a.z); a.w = fmaf(w, x.w * y.w, a.w);
}
__device__ __forceinline__ void add4(float4& a, float4 x) {
    a.x += x.x; a.y += x.y; a.z += x.z; a.w += x.w;
}

// classic 20-float-window forms (mask_pass / fallback kernel only)
__device__ __forceinline__ void convg(const float* __restrict__ row, int cb,
                                      const float* __restrict__ g, float out[4]) {
    float w[20];
    #pragma unroll
    for (int i = 0; i < 5; ++i) {
        float4 v = ld4s(row + cb + 4 * i);
        w[4*i+0] = v.x; w[4*i+1] = v.y; w[4*i+2] = v.z; w[4*i+3] = v.w;
    }
    #pragma unroll
    for (int j = 0; j < 4; ++j) {
        float a = 0.0f;
        #pragma unroll
        for (int k = 0; k < 11; ++k) a = fmaf(g[k], w[3 + j + k], a);
        out[j] = a;
    }
}

__device__ __forceinline__ void convb(const float* __restrict__ row, int cb,
                                      float out[4]) {
    float w[20];
    #pragma unroll
    for (int i = 0; i < 5; ++i) {
        float4 v = ld4s(row + cb + 4 * i);
        w[4*i+0] = v.x; w[4*i+1] = v.y; w[4*i+2] = v.z; w[4*i+3] = v.w;
    }
    #pragma unroll
    for (int j = 0; j < 4; ++j) {
        float a = 0.0f;
        #pragma unroll
        for (int k = 0; k < 11; ++k) a += w[3 + j + k];
        out[j] = a;
    }
}

// ---------------------------------------------------------------------------
// mask precompute: box-filter match (11x11), threshold, store uint8 per pixel.
// Accumulates the full denominator sum(mask) into acc[1]; block (0,0,0)
// also writes the gaussian weight table.
// ---------------------------------------------------------------------------
__global__ __launch_bounds__(256) void mask_pass(
    const float* __restrict__ match, unsigned char* __restrict__ maskbuf,
    float* __restrict__ gw, double* __restrict__ acc)
{
    __shared__ __align__(16) float raw[MRAWH][LDSW];
    __shared__ __align__(16) float vs[MTH][LDSW];
    __shared__ float red[4];

    const int tid = threadIdx.x;
    const int b = blockIdx.z;
    const int x0 = blockIdx.x * MTW - 8;     // global x of LDS col 0 (aligned)
    const int y0 = blockIdx.y * MTH - 5;
    const float* pm = match + (size_t)b * (IMH * IMW);

    // one thread of one block writes the weight table (read only by the
    // LATER ssim_main_pm launch -> stream-order safe)
    if (tid == 0 && blockIdx.x == 0 && blockIdx.y == 0 && b == 0) {
        float t[11];
        float s = 0.0f;
        for (int i = 0; i < 11; ++i) {
            float d = (float)(i - 5);
            t[i] = expf(-(d * d) / 4.5f);
            s += t[i];
        }
        for (int i = 0; i < 11; ++i) gw[i] = t[i] / s;
    }

    // stage 74 rows x 20 quads (cols x0 .. x0+79), zero pad OOB
    for (int t = tid; t < MRAWH * NQ; t += 256) {
        int r = t / NQ, q = t - r * NQ;
        int gy = y0 + r;
        int gx = x0 + 4 * q;
        float4 v = make_float4(0.f, 0.f, 0.f, 0.f);
        if ((unsigned)gy < IMH) {
            if ((unsigned)gx <= (IMW - 4)) {
                v = ld4s(pm + gy * IMW + gx);
            } else {
                float tmp[4];
                #pragma unroll
                for (int e = 0; e < 4; ++e) {
                    int x = gx + e;
                    bool ok = (unsigned)x < IMW;
                    tmp[e] = ok ? pm[gy * IMW + x] : 0.0f;
                }
                v = make_float4(tmp[0], tmp[1], tmp[2], tmp[3]);
            }
        }
        st4s(&raw[r][4 * q], v);
    }
    __syncthreads();

    // vertical box: 64 rows x 20 quads
    for (int t = tid; t < MTH * NQ; t += 256) {
        int r = t / NQ, q = t - r * NQ;
        int cq = 4 * q;
        float4 a = make_float4(0.f, 0.f, 0.f, 0.f);
        #pragma unroll
        for (int k = 0; k < 11; ++k) add4(a, ld4s(&raw[r + k][cq]));
        st4s(&vs[r][cq], a);
    }
    __syncthreads();

    // horizontal box + threshold: 64 rows x 16 quads
    float den = 0.0f;
    for (int t = tid; t < MTH * 16; t += 256) {
        int r = t >> 4, q = t & 15;
        float mb[4];
        convb(vs[r], 4 * q, mb);
        unsigned char bits[4];
        #pragma unroll
        for (int j = 0; j < 4; ++j) {
            float m = mb[j] * (1.0f / 121.0f) + 1e-7f;
            bool on = m > 0.5f;
            bits[j] = (unsigned char)on;
            den += on ? (1.0f + 1e-7f) : 1e-7f;
        }
        int gy = blockIdx.y * MTH + r;
        int gx = blockIdx.x * MTW + 4 * q;
        *(uchar4*)(maskbuf + ((size_t)b << 18) + (gy << 9) + gx) =
            make_uchar4(bits[0], bits[1], bits[2], bits[3]);
    }

    for (int off = 32; off > 0; off >>= 1) den += __shfl_down(den, off);
    if ((tid & 63) == 0) red[tid >> 6] = den;
    __syncthreads();
    if (tid == 0)
        atomicAdd(&acc[1], (double)(red[0] + red[1] + red[2] + red[3]));
}

// ---------------------------------------------------------------------------
// main SSIM kernel: 2 rings + 4 fld arrays (A,B,S,P), LDS 22.9 KB.
// V phase: f2 over 320 units. H phase: f2 streaming, 4 fields.
// __launch_bounds__(256,5). Grid 8x8x48 = 3072.
// ---------------------------------------------------------------------------
__global__ __launch_bounds__(256, 5) void ssim_main_pm(
    const float* __restrict__ img1, const float* __restrict__ img2,
    const unsigned char* __restrict__ maskbuf,
    const float* __restrict__ gw, double* __restrict__ acc)
{
    __shared__ __align__(16) float ring1[RINGR][LDSW];
    __shared__ __align__(16) float ring2[RINGR][LDSW];
    __shared__ __align__(16) float fld[4][SUP][LDSW];
    __shared__ float redn[4];

    const int tid = threadIdx.x;
    const int bc = blockIdx.z;
    const int b = bc / CHANS;
    const int c = bc - b * CHANS;
    const int ystart = blockIdx.y * STRIPH;
    const int bxg = blockIdx.x;
    const int bx0 = bxg * STRIPW - 8;   // global x of LDS col 0

    const float* p1 = img1 + (size_t)(b * CHANS + c) * (IMH * IMW);
    const float* p2 = img2 + (size_t)(b * CHANS + c) * (IMH * IMW);
    const unsigned char* pmk = maskbuf + ((size_t)b << 18);

    // weights: uniform pointer + constant offsets -> scalar loads (SGPRs)
    float g[11];
    #pragma unroll
    for (int i = 0; i < 11; ++i) g[i] = gw[i];

    float num = 0.0f;
    const bool colsafe = (bx0 >= 0) && (bx0 + 4 * NQ <= IMW);  // interior in x

    auto stage = [&](int gy0, int nrows) {
        // nrows*NQ <= 200 < 256: single shot, no loop
        if (tid < nrows * NQ) {
            int r = tid / NQ, q = tid - r * NQ;
            int gy = gy0 + r;
            int slot = (gy + 36) % RINGR;
            int gx = bx0 + 4 * q;
            float4 v1 = make_float4(0.f, 0.f, 0.f, 0.f), v2 = v1;
            if ((unsigned)gy < IMH) {
                if (colsafe || (unsigned)gx <= (IMW - 4)) {
                    v1 = ld4s(p1 + gy * IMW + gx);
                    v2 = ld4s(p2 + gy * IMW + gx);
                } else {
                    float t1[4], t2[4];
                    #pragma unroll
                    for (int e = 0; e < 4; ++e) {
                        int x = gx + e;
                        bool ok = (unsigned)x < IMW;
                        int off = gy * IMW + (ok ? x : 0);
                        t1[e] = ok ? p1[off] : 0.0f;
                        t2[e] = ok ? p2[off] : 0.0f;
                    }
                    v1 = make_float4(t1[0], t1[1], t1[2], t1[3]);
                    v2 = make_float4(t2[0], t2[1], t2[2], t2[3]);
                }
            }
            st4s(&ring1[slot][4 * q], v1);
            st4s(&ring2[slot][4 * q], v2);
        }
    };

    // prologue: raw rows ystart-5 .. ystart+4
    stage(ystart - 5, 10);

    for (int s = 0; s < NSUP; ++s) {
        const int ybase = ystart + s * SUP;

        // stage the 8 new raw rows this super needs (ybase+5 .. ybase+12).
        stage(ybase + 5, SUP);
        __syncthreads();   // B1: staging visible; fld free (H of s-1 done)

        // ---- vertical pass: 320 float2 units over 256 threads ----
        // unit u -> row r = u/40, half-quad hq = u%40 (cols 2hq, 2hq+1).
        // fields: a1=conv(x1), a2=conv(x2), aS=conv(x1^2+x2^2), aP=conv(x1x2)
        #pragma unroll
        for (int pass = 0; pass < 2; ++pass) {
            if (pass == 0 || tid < SUP * 40 - 256) {   // pass1: 64 threads
                const int u = tid + pass * 256;
                const int r = u / 40, hq = u - r * 40;
                const int cw = 2 * hq;
                int sr = (ybase + r + 31) % RINGR;     // row (y-5)
                float2 a1 = make_float2(0.f, 0.f), a2 = a1, aS = a1, aP = a1;
                #pragma unroll
                for (int k = 0; k < 11; ++k) {
                    float2 x1 = *(const float2*)&ring1[sr][cw];
                    float2 x2 = *(const float2*)&ring2[sr][cw];
                    float w = g[k];
                    a1.x = fmaf(w, x1.x, a1.x);
                    a1.y = fmaf(w, x1.y, a1.y);
                    a2.x = fmaf(w, x2.x, a2.x);
                    a2.y = fmaf(w, x2.y, a2.y);
                    aS.x = fmaf(w, fmaf(x2.x, x2.x, x1.x * x1.x), aS.x);
                    aS.y = fmaf(w, fmaf(x2.y, x2.y, x1.y * x1.y), aS.y);
                    aP.x = fmaf(w, x1.x * x2.x, aP.x);
                    aP.y = fmaf(w, x1.y * x2.y, aP.y);
                    sr++; if (sr >= RINGR) sr -= RINGR;
                }
                *(float2*)&fld[0][r][cw] = a1;
                *(float2*)&fld[1][r][cw] = a2;
                *(float2*)&fld[2][r][cw] = aS;
                *(float2*)&fld[3][r][cw] = aP;
            }
        }
        __syncthreads();   // B2: fld visible; ring free for next stage

        // ---- horizontal pass + SSIM: 8 rows x 32 float2 cols, 256 thr ----
        // STREAMING form: 7 float2 loads per field, ascending-k per output.
        {
            int r = tid >> 5, h = tid & 31;
            const int c0 = 2 * h + 2;   // loads cols c0 .. c0+13
            float mu1[2], mu2[2], hS[2], hP[2];
            auto convg2s = [&](const float* __restrict__ row, float out[2]) {
                float a0 = 0.0f, a1 = 0.0f;
                #pragma unroll
                for (int i = 0; i < 7; ++i) {
                    float2 v = *(const float2*)(row + c0 + 2 * i);
                    // out0 taps: cols c0+1..c0+11 (k = j-1, j = col-c0)
                    // out1 taps: cols c0+2..c0+12 (k = j-2)
                    if (i >= 1 && i <= 5) a0 = fmaf(g[2*i-1], v.x, a0);
                    if (i <= 5)           a0 = fmaf(g[2*i],   v.y, a0);
                    if (i >= 1)           a1 = fmaf(g[2*i-2], v.x, a1);
                    if (i >= 1 && i <= 5) a1 = fmaf(g[2*i-1], v.y, a1);
                }
                out[0] = a0; out[1] = a1;
            };
            convg2s(fld[0][r], mu1);
            convg2s(fld[1][r], mu2);
            convg2s(fld[2][r], hS);
            convg2s(fld[3][r], hP);

            int gy = ybase + r;
            int gx = bxg * STRIPW + 2 * h;
            uchar2 mk = *(const uchar2*)(pmk + (gy << 9) + gx);
            const unsigned char mkv[2] = {mk.x, mk.y};
            #pragma unroll
            for (int j = 0; j < 2; ++j) {
                float mu1s = mu1[j] * mu1[j];
                float mu2s = mu2[j] * mu2[j];
                float mu12 = mu1[j] * mu2[j];
                float sgsum = hS[j] - mu1s - mu2s;   // sigma1_sq + sigma2_sq
                float sg12  = hP[j] - mu12;          // sigma12
                float ssim = ((2.0f * mu12 + 1e-4f) * (2.0f * sg12 + 9e-4f)) /
                             ((mu1s + mu2s + 1e-4f) * (sgsum + 9e-4f));
                float mask = mkv[j] ? (1.0f + 1e-7f) : 1e-7f;
                num += (1.0f - ssim) * mask;
            }
        }
    }

    // ---- block reduction: wave shuffle (width 64) then cross-wave LDS ----
    for (int off = 32; off > 0; off >>= 1) num += __shfl_down(num, off);
    if ((tid & 63) == 0) redn[tid >> 6] = num;
    __syncthreads();
    if (tid == 0)
        atomicAdd(&acc[0], (double)(redn[0] + redn[1] + redn[2] + redn[3]));
    (void)c;
}

// ---------------------------------------------------------------------------
// fallback: round-2 all-in-one kernel (used only if ws too small for mask)
// ---------------------------------------------------------------------------
#define FBSTRIPH 256
#define FBNSUP (FBSTRIPH / SUP)
__global__ __launch_bounds__(256) void ssim_main_fb(
    const float* __restrict__ img1, const float* __restrict__ img2,
    const float* __restrict__ match, double* __restrict__ acc)
{
    __shared__ __align__(16) float ring1[RINGR][LDSW];
    __shared__ __align__(16) float ring2[RINGR][LDSW];
    __shared__ __align__(16) float ringm[RINGR][LDSW];
    __shared__ __align__(16) float fld[6][SUP][LDSW];
    __shared__ float redn[4], redd[4];

    const int tid = threadIdx.x;
    const int bc = blockIdx.z;
    const int b = bc / CHANS;
    const int c = bc - b * CHANS;
    const int ystart = blockIdx.y * FBSTRIPH;
    const int bx0 = blockIdx.x * STRIPW - 8;

    const float* p1 = img1 + (size_t)(b * CHANS + c) * (IMH * IMW);
    const float* p2 = img2 + (size_t)(b * CHANS + c) * (IMH * IMW);
    const float* pm = match + (size_t)b * (IMH * IMW);

    float g[11];
    {
        float s = 0.0f;
        #pragma unroll
        for (int i = 0; i < 11; ++i) {
            float d = (float)(i - 5);
            g[i] = expf(-(d * d) / 4.5f);
            s += g[i];
        }
        #pragma unroll
        for (int i = 0; i < 11; ++i) g[i] /= s;
    }

    float num = 0.0f, den = 0.0f;

    auto stage = [&](int gy0, int nrows) {
        for (int t = tid; t < nrows * NQ; t += 256) {
            int r = t / NQ, q = t - r * NQ;
            int gy = gy0 + r;
            int slot = (gy + 36) % RINGR;
            int gx = bx0 + 4 * q;
            float4 v1, v2, vm;
            if ((unsigned)gy < IMH && (unsigned)gx <= (IMW - 4)) {
                v1 = ld4s(p1 + gy * IMW + gx);
                v2 = ld4s(p2 + gy * IMW + gx);
                vm = ld4s(pm + gy * IMW + gx);
            } else if ((unsigned)gy < IMH) {
                float t1[4], t2[4], tm[4];
                #pragma unroll
                for (int e = 0; e < 4; ++e) {
                    int x = gx + e;
                    bool ok = (unsigned)x < IMW;
                    int off = gy * IMW + (ok ? x : 0);
                    t1[e] = ok ? p1[off] : 0.0f;
                    t2[e] = ok ? p2[off] : 0.0f;
                    tm[e] = ok ? pm[off] : 0.0f;
                }
                v1 = make_float4(t1[0], t1[1], t1[2], t1[3]);
                v2 = make_float4(t2[0], t2[1], t2[2], t2[3]);
                vm = make_float4(tm[0], tm[1], tm[2], tm[3]);
            } else {
                v1 = v2 = vm = make_float4(0.f, 0.f, 0.f, 0.f);
            }
            st4s(&ring1[slot][4 * q], v1);
            st4s(&ring2[slot][4 * q], v2);
            st4s(&ringm[slot][4 * q], vm);
        }
    };

    stage(ystart - 5, 10);

    for (int s = 0; s < FBNSUP; ++s) {
        const int ybase = ystart + s * SUP;
        stage(ybase + 5, SUP);
        __syncthreads();

        if (tid < SUP * NQ) {
            int r = tid / NQ, q = tid - r * NQ;
            int cq = 4 * q;
            int sr = (ybase + r + 31) % RINGR;
            float4 a1 = make_float4(0,0,0,0), a2 = a1, a3 = a1,
                   a4 = a1, a5 = a1, am = a1;
            #pragma unroll
            for (int k = 0; k < 11; ++k) {
                float4 x1 = ld4s(&ring1[sr][cq]);
                float4 x2 = ld4s(&ring2[sr][cq]);
                float4 xm = ld4s(&ringm[sr][cq]);
                float w = g[k];
                fma4(a1, w, x1);
                fma4(a2, w, x2);
                fma4m(a3, w, x1, x1);
                fma4m(a4, w, x2, x2);
                fma4m(a5, w, x1, x2);
                add4(am, xm);
                sr++; if (sr >= RINGR) sr -= RINGR;
            }
            st4s(&fld[0][r][cq], a1);
            st4s(&fld[1][r][cq], a2);
            st4s(&fld[2][r][cq], a3);
            st4s(&fld[3][r][cq], a4);
            st4s(&fld[4][r][cq], a5);
            st4s(&fld[5][r][cq], am);
        }
        __syncthreads();

        if (tid < SUP * 16) {
            int r = tid >> 4, q = tid & 15;
            int cb = 4 * q;
            float mu1[4], mu2[4], m11[4], m22[4], m12[4], mb[4];
            convg(fld[0][r], cb, g, mu1);
            convg(fld[1][r], cb, g, mu2);
            convg(fld[2][r], cb, g, m11);
            convg(fld[3][r], cb, g, m22);
            convg(fld[4][r], cb, g, m12);
            convb(fld[5][r], cb, mb);
            #pragma unroll
            for (int j = 0; j < 4; ++j) {
                float mu1s = mu1[j] * mu1[j];
                float mu2s = mu2[j] * mu2[j];
                float mu12 = mu1[j] * mu2[j];
                float sg1  = m11[j] - mu1s;
                float sg2  = m22[j] - mu2s;
                float sg12 = m12[j] - mu12;
                float ssim = ((2.0f * mu12 + 1e-4f) * (2.0f * sg12 + 9e-4f)) /
                             ((mu1s + mu2s + 1e-4f) * (sg1 + sg2 + 9e-4f));
                float m = mb[j] * (1.0f / 121.0f) + 1e-7f;
                float mask = (m > 0.5f) ? (1.0f + 1e-7f) : 1e-7f;
                num += (1.0f - ssim) * mask;
                den += mask;
            }
        }
    }

    for (int off = 32; off > 0; off >>= 1) {
        num += __shfl_down(num, off);
        den += __shfl_down(den, off);
    }
    int wave = tid >> 6;
    int lane = tid & 63;
    if (lane == 0) { redn[wave] = num; redd[wave] = den; }
    __syncthreads();
    if (tid == 0) {
        float n = redn[0] + redn[1] + redn[2] + redn[3];
        atomicAdd(&acc[0], (double)n);
        if (c == 0) {
            float d = redd[0] + redd[1] + redd[2] + redd[3];
            atomicAdd(&acc[1], (double)d);
        }
    }
}

__global__ void finalize(const double* __restrict__ acc, float* __restrict__ out) {
    out[0] = (float)(acc[0] / acc[1] / 3.0);
}

extern "C" void kernel_launch(void* const* d_in, const int* in_sizes, int n_in,
                              void* d_out, int out_size, void* d_ws, size_t ws_size,
                              hipStream_t stream) {
    const float* img1  = (const float*)d_in[0];
    const float* img2  = (const float*)d_in[1];
    const float* match = (const float*)d_in[2];
    float* out = (float*)d_out;
    double* acc = (double*)d_ws;                       // 16 B @ ws+0

    const size_t mask_need = 128 + (size_t)BATCH * IMH * IMW;  // 4,194,432 B
    const bool premask = (ws_size >= mask_need);
    float* gw = (float*)((char*)d_ws + 64);            // 44 B @ ws+64

    // zero acc[0..1] (doubles: all-zero bytes == +0.0); capturable async op
    hipMemsetAsync(d_ws, 0, 16, stream);

    dim3 block(256, 1, 1);
    if (premask) {
        unsigned char* mbuf = (unsigned char*)d_ws + 128;
        dim3 mgrid(IMW / MTW, IMH / MTH, BATCH);               // 8 x 8 x 16
        mask_pass<<<mgrid, block, 0, stream>>>(match, mbuf, gw, acc);
        dim3 grid(IMW / STRIPW, IMH / STRIPH, BATCH * CHANS);  // 8 x 8 x 48
        ssim_main_pm<<<grid, block, 0, stream>>>(img1, img2, mbuf, gw, acc);
    } else {
        dim3 grid(IMW / STRIPW, IMH / FBSTRIPH, BATCH * CHANS);
        ssim_main_fb<<<grid, block, 0, stream>>>(img1, img2, match, acc);
    }

    finalize<<<1, 1, 0, stream>>>(acc, out);
}

// Round 10
// 208.462 us; speedup vs baseline: 1.2401x; 1.0361x over previous
//
#include <hip/hip_runtime.h>

// SSIM_13443247637111 — fused separable SSIM, V-first ring-buffer design.
// B=16, CH=3, 512x512, 11x11 gaussian sigma 1.5, zero padding 5.
//
// Round-12 structure (V y-register-blocking):
//  - ROUND-9 POST-MORTEM: predictions hit (99.3us, conflicts 1.389e7,
//    absmax 0). LDS cycle accounting: ~247 wave-LDS-insts/super-block
//    (~59us of the 99) -> LDS INSTRUCTION COUNT is the binding term, not
//    banks (3 failed remaps), not VALU (floor ~18us).
//  - V PHASE Y-BLOCKING (rowblock=2): each thread owns 2 output rows of one
//    column-pair. Reads the 12 contributing ring rows ONCE each (24 f2
//    reads vs 44 for 2 rows), computes S=x1^2+x2^2 / P=x1*x2 once per row,
//    and fmas into 2 accumulator sets with STATIC weight indexing
//    (out0: g[t] t=0..10; out1: g[t-1] t=1..11; fully unrolled).
//    V LDS reads -45%, V VALU -19%, writes unchanged. 160 threads.
//  - Register note: +8 f2 accumulators; (256,5) cap squeezes ~56 -> 48.
//    Mild (1.17x) squeeze, expected no spills. Canary: WRITE_SIZE ~96 B.
//  - Frozen from R9: 4-field algebra, f2-H streaming, premask, memset-init,
//    LDS 22.9 KB, grid 8x8x48 = 3072.

#define BATCH 16
#define CHANS 3
#define IMH 512
#define IMW 512
#define STRIPW 64
#define STRIPH 64
#define RINGR 18            // raw rows resident: y-5 .. y+12 for an 8-row super
#define LDSW 84             // padded row width; col c <-> x = bx*64 + c - 8
#define SUP 8               // output rows per super-iteration
#define NSUP (STRIPH / SUP) // 8
#define NQ 20               // float4 quads per staged row (80 cols)

// mask-pass tile
#define MTW 64
#define MTH 64
#define MRAWH 74            // MTH + 10 halo rows

__device__ __forceinline__ float4 ld4s(const float* p) { return *(const float4*)p; }
__device__ __forceinline__ void st4s(float* p, float4 v) { *(float4*)p = v; }
__device__ __forceinline__ void fma4(float4& a, float w, float4 x) {
    a.x = fmaf(w, x.x, a.x); a.y = fmaf(w, x.y, a.y);
    a.z = fmaf(w, x.z, a.z); a.w = fmaf(w, x.w, a.w);
}
__device__ __forceinline__ void fma4m(float4& a, float w, float4 x, float4 y) {
    a.x = fmaf(w, x.x * y.x, a.x); a.y = fmaf(w, x.y * y.y, a.y);
    a.z = fmaf(w, x.z * y.z, a.z); a.w = fmaf(w, x.w * y.w, a.w);
}
__device__ __forceinline__ void add4(float4& a, float4 x) {
    a.x += x.x; a.y += x.y; a.z += x.z; a.w += x.w;
}
__device__ __forceinline__ void fma2(float2& a, float w, float2 x) {
    a.x = fmaf(w, x.x, a.x); a.y = fmaf(w, x.y, a.y);
}

// classic 20-float-window forms (mask_pass / fallback kernel only)
__device__ __forceinline__ void convg(const float* __restrict__ row, int cb,
                                      const float* __restrict__ g, float out[4]) {
    float w[20];
    #pragma unroll
    for (int i = 0; i < 5; ++i) {
        float4 v = ld4s(row + cb + 4 * i);
        w[4*i+0] = v.x; w[4*i+1] = v.y; w[4*i+2] = v.z; w[4*i+3] = v.w;
    }
    #pragma unroll
    for (int j = 0; j < 4; ++j) {
        float a = 0.0f;
        #pragma unroll
        for (int k = 0; k < 11; ++k) a = fmaf(g[k], w[3 + j + k], a);
        out[j] = a;
    }
}

__device__ __forceinline__ void convb(const float* __restrict__ row, int cb,
                                      float out[4]) {
    float w[20];
    #pragma unroll
    for (int i = 0; i < 5; ++i) {
        float4 v = ld4s(row + cb + 4 * i);
        w[4*i+0] = v.x; w[4*i+1] = v.y; w[4*i+2] = v.z; w[4*i+3] = v.w;
    }
    #pragma unroll
    for (int j = 0; j < 4; ++j) {
        float a = 0.0f;
        #pragma unroll
        for (int k = 0; k < 11; ++k) a += w[3 + j + k];
        out[j] = a;
    }
}

// ---------------------------------------------------------------------------
// mask precompute: box-filter match (11x11), threshold, store uint8 per pixel.
// Accumulates the full denominator sum(mask) into acc[1]; block (0,0,0)
// also writes the gaussian weight table.
// ---------------------------------------------------------------------------
__global__ __launch_bounds__(256) void mask_pass(
    const float* __restrict__ match, unsigned char* __restrict__ maskbuf,
    float* __restrict__ gw, double* __restrict__ acc)
{
    __shared__ __align__(16) float raw[MRAWH][LDSW];
    __shared__ __align__(16) float vs[MTH][LDSW];
    __shared__ float red[4];

    const int tid = threadIdx.x;
    const int b = blockIdx.z;
    const int x0 = blockIdx.x * MTW - 8;     // global x of LDS col 0 (aligned)
    const int y0 = blockIdx.y * MTH - 5;
    const float* pm = match + (size_t)b * (IMH * IMW);

    // one thread of one block writes the weight table (read only by the
    // LATER ssim_main_pm launch -> stream-order safe)
    if (tid == 0 && blockIdx.x == 0 && blockIdx.y == 0 && b == 0) {
        float t[11];
        float s = 0.0f;
        for (int i = 0; i < 11; ++i) {
            float d = (float)(i - 5);
            t[i] = expf(-(d * d) / 4.5f);
            s += t[i];
        }
        for (int i = 0; i < 11; ++i) gw[i] = t[i] / s;
    }

    // stage 74 rows x 20 quads (cols x0 .. x0+79), zero pad OOB
    for (int t = tid; t < MRAWH * NQ; t += 256) {
        int r = t / NQ, q = t - r * NQ;
        int gy = y0 + r;
        int gx = x0 + 4 * q;
        float4 v = make_float4(0.f, 0.f, 0.f, 0.f);
        if ((unsigned)gy < IMH) {
            if ((unsigned)gx <= (IMW - 4)) {
                v = ld4s(pm + gy * IMW + gx);
            } else {
                float tmp[4];
                #pragma unroll
                for (int e = 0; e < 4; ++e) {
                    int x = gx + e;
                    bool ok = (unsigned)x < IMW;
                    tmp[e] = ok ? pm[gy * IMW + x] : 0.0f;
                }
                v = make_float4(tmp[0], tmp[1], tmp[2], tmp[3]);
            }
        }
        st4s(&raw[r][4 * q], v);
    }
    __syncthreads();

    // vertical box: 64 rows x 20 quads
    for (int t = tid; t < MTH * NQ; t += 256) {
        int r = t / NQ, q = t - r * NQ;
        int cq = 4 * q;
        float4 a = make_float4(0.f, 0.f, 0.f, 0.f);
        #pragma unroll
        for (int k = 0; k < 11; ++k) add4(a, ld4s(&raw[r + k][cq]));
        st4s(&vs[r][cq], a);
    }
    __syncthreads();

    // horizontal box + threshold: 64 rows x 16 quads
    float den = 0.0f;
    for (int t = tid; t < MTH * 16; t += 256) {
        int r = t >> 4, q = t & 15;
        float mb[4];
        convb(vs[r], 4 * q, mb);
        unsigned char bits[4];
        #pragma unroll
        for (int j = 0; j < 4; ++j) {
            float m = mb[j] * (1.0f / 121.0f) + 1e-7f;
            bool on = m > 0.5f;
            bits[j] = (unsigned char)on;
            den += on ? (1.0f + 1e-7f) : 1e-7f;
        }
        int gy = blockIdx.y * MTH + r;
        int gx = blockIdx.x * MTW + 4 * q;
        *(uchar4*)(maskbuf + ((size_t)b << 18) + (gy << 9) + gx) =
            make_uchar4(bits[0], bits[1], bits[2], bits[3]);
    }

    for (int off = 32; off > 0; off >>= 1) den += __shfl_down(den, off);
    if ((tid & 63) == 0) red[tid >> 6] = den;
    __syncthreads();
    if (tid == 0)
        atomicAdd(&acc[1], (double)(red[0] + red[1] + red[2] + red[3]));
}

// ---------------------------------------------------------------------------
// main SSIM kernel: 2 rings + 4 fld arrays (A,B,S,P), LDS 22.9 KB.
// V phase: y-blocked, 160 threads x (2 rows x f2 col-pair), 12 reads/thread.
// H phase: f2 streaming, 4 fields. __launch_bounds__(256,5). Grid 8x8x48.
// ---------------------------------------------------------------------------
__global__ __launch_bounds__(256, 5) void ssim_main_pm(
    const float* __restrict__ img1, const float* __restrict__ img2,
    const unsigned char* __restrict__ maskbuf,
    const float* __restrict__ gw, double* __restrict__ acc)
{
    __shared__ __align__(16) float ring1[RINGR][LDSW];
    __shared__ __align__(16) float ring2[RINGR][LDSW];
    __shared__ __align__(16) float fld[4][SUP][LDSW];
    __shared__ float redn[4];

    const int tid = threadIdx.x;
    const int bc = blockIdx.z;
    const int b = bc / CHANS;
    const int c = bc - b * CHANS;
    const int ystart = blockIdx.y * STRIPH;
    const int bxg = blockIdx.x;
    const int bx0 = bxg * STRIPW - 8;   // global x of LDS col 0

    const float* p1 = img1 + (size_t)(b * CHANS + c) * (IMH * IMW);
    const float* p2 = img2 + (size_t)(b * CHANS + c) * (IMH * IMW);
    const unsigned char* pmk = maskbuf + ((size_t)b << 18);

    // weights: uniform pointer + constant offsets -> scalar loads (SGPRs)
    float g[11];
    #pragma unroll
    for (int i = 0; i < 11; ++i) g[i] = gw[i];

    float num = 0.0f;
    const bool colsafe = (bx0 >= 0) && (bx0 + 4 * NQ <= IMW);  // interior in x

    auto stage = [&](int gy0, int nrows) {
        // nrows*NQ <= 200 < 256: single shot, no loop
        if (tid < nrows * NQ) {
            int r = tid / NQ, q = tid - r * NQ;
            int gy = gy0 + r;
            int slot = (gy + 36) % RINGR;
            int gx = bx0 + 4 * q;
            float4 v1 = make_float4(0.f, 0.f, 0.f, 0.f), v2 = v1;
            if ((unsigned)gy < IMH) {
                if (colsafe || (unsigned)gx <= (IMW - 4)) {
                    v1 = ld4s(p1 + gy * IMW + gx);
                    v2 = ld4s(p2 + gy * IMW + gx);
                } else {
                    float t1[4], t2[4];
                    #pragma unroll
                    for (int e = 0; e < 4; ++e) {
                        int x = gx + e;
                        bool ok = (unsigned)x < IMW;
                        int off = gy * IMW + (ok ? x : 0);
                        t1[e] = ok ? p1[off] : 0.0f;
                        t2[e] = ok ? p2[off] : 0.0f;
                    }
                    v1 = make_float4(t1[0], t1[1], t1[2], t1[3]);
                    v2 = make_float4(t2[0], t2[1], t2[2], t2[3]);
                }
            }
            st4s(&ring1[slot][4 * q], v1);
            st4s(&ring2[slot][4 * q], v2);
        }
    };

    // prologue: raw rows ystart-5 .. ystart+4
    stage(ystart - 5, 10);

    for (int s = 0; s < NSUP; ++s) {
        const int ybase = ystart + s * SUP;

        // stage the 8 new raw rows this super needs (ybase+5 .. ybase+12).
        stage(ybase + 5, SUP);
        __syncthreads();   // B1: staging visible; fld free (H of s-1 done)

        // ---- vertical pass: y-blocked, 160 threads ----
        // thread -> (rb, hq): rb = tid/40 in 0..3 owns output rows
        // ybase+2rb, ybase+2rb+1 for col-pair hq. Reads the 12 contributing
        // ring rows once each; static weight indexing (fully unrolled):
        //   out0 taps t=0..10 with g[t]; out1 taps t=1..11 with g[t-1].
        if (tid < 160) {
            const int rb = tid / 40;
            const int hq = tid - rb * 40;
            const int cw = 2 * hq;
            const int r0 = 2 * rb;               // local output row index
            int sr = (ybase + r0 + 31) % RINGR;  // absolute row (y0 - 5)
            float2 z = make_float2(0.f, 0.f);
            float2 A0 = z, B0 = z, S0 = z, P0 = z;
            float2 A1 = z, B1 = z, S1 = z, P1 = z;
            #pragma unroll
            for (int t = 0; t < 12; ++t) {
                float2 x1 = *(const float2*)&ring1[sr][cw];
                float2 x2 = *(const float2*)&ring2[sr][cw];
                float2 sv, pv;
                sv.x = fmaf(x2.x, x2.x, x1.x * x1.x);
                sv.y = fmaf(x2.y, x2.y, x1.y * x1.y);
                pv.x = x1.x * x2.x;
                pv.y = x1.y * x2.y;
                if (t <= 10) {
                    float w = g[t];
                    fma2(A0, w, x1); fma2(B0, w, x2);
                    fma2(S0, w, sv); fma2(P0, w, pv);
                }
                if (t >= 1) {
                    float w = g[t - 1];
                    fma2(A1, w, x1); fma2(B1, w, x2);
                    fma2(S1, w, sv); fma2(P1, w, pv);
                }
                sr++; if (sr >= RINGR) sr -= RINGR;
            }
            *(float2*)&fld[0][r0][cw] = A0; *(float2*)&fld[0][r0 + 1][cw] = A1;
            *(float2*)&fld[1][r0][cw] = B0; *(float2*)&fld[1][r0 + 1][cw] = B1;
            *(float2*)&fld[2][r0][cw] = S0; *(float2*)&fld[2][r0 + 1][cw] = S1;
            *(float2*)&fld[3][r0][cw] = P0; *(float2*)&fld[3][r0 + 1][cw] = P1;
        }
        __syncthreads();   // B2: fld visible; ring free for next stage

        // ---- horizontal pass + SSIM: 8 rows x 32 float2 cols, 256 thr ----
        // STREAMING form: 7 float2 loads per field, ascending-k per output.
        {
            int r = tid >> 5, h = tid & 31;
            const int c0 = 2 * h + 2;   // loads cols c0 .. c0+13
            float mu1[2], mu2[2], hS[2], hP[2];
            auto convg2s = [&](const float* __restrict__ row, float out[2]) {
                float a0 = 0.0f, a1 = 0.0f;
                #pragma unroll
                for (int i = 0; i < 7; ++i) {
                    float2 v = *(const float2*)(row + c0 + 2 * i);
                    // out0 taps: cols c0+1..c0+11 (k = j-1, j = col-c0)
                    // out1 taps: cols c0+2..c0+12 (k = j-2)
                    if (i >= 1 && i <= 5) a0 = fmaf(g[2*i-1], v.x, a0);
                    if (i <= 5)           a0 = fmaf(g[2*i],   v.y, a0);
                    if (i >= 1)           a1 = fmaf(g[2*i-2], v.x, a1);
                    if (i >= 1 && i <= 5) a1 = fmaf(g[2*i-1], v.y, a1);
                }
                out[0] = a0; out[1] = a1;
            };
            convg2s(fld[0][r], mu1);
            convg2s(fld[1][r], mu2);
            convg2s(fld[2][r], hS);
            convg2s(fld[3][r], hP);

            int gy = ybase + r;
            int gx = bxg * STRIPW + 2 * h;
            uchar2 mk = *(const uchar2*)(pmk + (gy << 9) + gx);
            const unsigned char mkv[2] = {mk.x, mk.y};
            #pragma unroll
            for (int j = 0; j < 2; ++j) {
                float mu1s = mu1[j] * mu1[j];
                float mu2s = mu2[j] * mu2[j];
                float mu12 = mu1[j] * mu2[j];
                float sgsum = hS[j] - mu1s - mu2s;   // sigma1_sq + sigma2_sq
                float sg12  = hP[j] - mu12;          // sigma12
                float ssim = ((2.0f * mu12 + 1e-4f) * (2.0f * sg12 + 9e-4f)) /
                             ((mu1s + mu2s + 1e-4f) * (sgsum + 9e-4f));
                float mask = mkv[j] ? (1.0f + 1e-7f) : 1e-7f;
                num += (1.0f - ssim) * mask;
            }
        }
    }

    // ---- block reduction: wave shuffle (width 64) then cross-wave LDS ----
    for (int off = 32; off > 0; off >>= 1) num += __shfl_down(num, off);
    if ((tid & 63) == 0) redn[tid >> 6] = num;
    __syncthreads();
    if (tid == 0)
        atomicAdd(&acc[0], (double)(redn[0] + redn[1] + redn[2] + redn[3]));
    (void)c;
}

// ---------------------------------------------------------------------------
// fallback: round-2 all-in-one kernel (used only if ws too small for mask)
// ---------------------------------------------------------------------------
#define FBSTRIPH 256
#define FBNSUP (FBSTRIPH / SUP)
__global__ __launch_bounds__(256) void ssim_main_fb(
    const float* __restrict__ img1, const float* __restrict__ img2,
    const float* __restrict__ match, double* __restrict__ acc)
{
    __shared__ __align__(16) float ring1[RINGR][LDSW];
    __shared__ __align__(16) float ring2[RINGR][LDSW];
    __shared__ __align__(16) float ringm[RINGR][LDSW];
    __shared__ __align__(16) float fld[6][SUP][LDSW];
    __shared__ float redn[4], redd[4];

    const int tid = threadIdx.x;
    const int bc = blockIdx.z;
    const int b = bc / CHANS;
    const int c = bc - b * CHANS;
    const int ystart = blockIdx.y * FBSTRIPH;
    const int bx0 = blockIdx.x * STRIPW - 8;

    const float* p1 = img1 + (size_t)(b * CHANS + c) * (IMH * IMW);
    const float* p2 = img2 + (size_t)(b * CHANS + c) * (IMH * IMW);
    const float* pm = match + (size_t)b * (IMH * IMW);

    float g[11];
    {
        float s = 0.0f;
        #pragma unroll
        for (int i = 0; i < 11; ++i) {
            float d = (float)(i - 5);
            g[i] = expf(-(d * d) / 4.5f);
            s += g[i];
        }
        #pragma unroll
        for (int i = 0; i < 11; ++i) g[i] /= s;
    }

    float num = 0.0f, den = 0.0f;

    auto stage = [&](int gy0, int nrows) {
        for (int t = tid; t < nrows * NQ; t += 256) {
            int r = t / NQ, q = t - r * NQ;
            int gy = gy0 + r;
            int slot = (gy + 36) % RINGR;
            int gx = bx0 + 4 * q;
            float4 v1, v2, vm;
            if ((unsigned)gy < IMH && (unsigned)gx <= (IMW - 4)) {
                v1 = ld4s(p1 + gy * IMW + gx);
                v2 = ld4s(p2 + gy * IMW + gx);
                vm = ld4s(pm + gy * IMW + gx);
            } else if ((unsigned)gy < IMH) {
                float t1[4], t2[4], tm[4];
                #pragma unroll
                for (int e = 0; e < 4; ++e) {
                    int x = gx + e;
                    bool ok = (unsigned)x < IMW;
                    int off = gy * IMW + (ok ? x : 0);
                    t1[e] = ok ? p1[off] : 0.0f;
                    t2[e] = ok ? p2[off] : 0.0f;
                    tm[e] = ok ? pm[off] : 0.0f;
                }
                v1 = make_float4(t1[0], t1[1], t1[2], t1[3]);
                v2 = make_float4(t2[0], t2[1], t2[2], t2[3]);
                vm = make_float4(tm[0], tm[1], tm[2], tm[3]);
            } else {
                v1 = v2 = vm = make_float4(0.f, 0.f, 0.f, 0.f);
            }
            st4s(&ring1[slot][4 * q], v1);
            st4s(&ring2[slot][4 * q], v2);
            st4s(&ringm[slot][4 * q], vm);
        }
    };

    stage(ystart - 5, 10);

    for (int s = 0; s < FBNSUP; ++s) {
        const int ybase = ystart + s * SUP;
        stage(ybase + 5, SUP);
        __syncthreads();

        if (tid < SUP * NQ) {
            int r = tid / NQ, q = tid - r * NQ;
            int cq = 4 * q;
            int sr = (ybase + r + 31) % RINGR;
            float4 a1 = make_float4(0,0,0,0), a2 = a1, a3 = a1,
                   a4 = a1, a5 = a1, am = a1;
            #pragma unroll
            for (int k = 0; k < 11; ++k) {
                float4 x1 = ld4s(&ring1[sr][cq]);
                float4 x2 = ld4s(&ring2[sr][cq]);
                float4 xm = ld4s(&ringm[sr][cq]);
                float w = g[k];
                fma4(a1, w, x1);
                fma4(a2, w, x2);
                fma4m(a3, w, x1, x1);
                fma4m(a4, w, x2, x2);
                fma4m(a5, w, x1, x2);
                add4(am, xm);
                sr++; if (sr >= RINGR) sr -= RINGR;
            }
            st4s(&fld[0][r][cq], a1);
            st4s(&fld[1][r][cq], a2);
            st4s(&fld[2][r][cq], a3);
            st4s(&fld[3][r][cq], a4);
            st4s(&fld[4][r][cq], a5);
            st4s(&fld[5][r][cq], am);
        }
        __syncthreads();

        if (tid < SUP * 16) {
            int r = tid >> 4, q = tid & 15;
            int cb = 4 * q;
            float mu1[4], mu2[4], m11[4], m22[4], m12[4], mb[4];
            convg(fld[0][r], cb, g, mu1);
            convg(fld[1][r], cb, g, mu2);
            convg(fld[2][r], cb, g, m11);
            convg(fld[3][r], cb, g, m22);
            convg(fld[4][r], cb, g, m12);
            convb(fld[5][r], cb, mb);
            #pragma unroll
            for (int j = 0; j < 4; ++j) {
                float mu1s = mu1[j] * mu1[j];
                float mu2s = mu2[j] * mu2[j];
                float mu12 = mu1[j] * mu2[j];
                float sg1  = m11[j] - mu1s;
                float sg2  = m22[j] - mu2s;
                float sg12 = m12[j] - mu12;
                float ssim = ((2.0f * mu12 + 1e-4f) * (2.0f * sg12 + 9e-4f)) /
                             ((mu1s + mu2s + 1e-4f) * (sg1 + sg2 + 9e-4f));
                float m = mb[j] * (1.0f / 121.0f) + 1e-7f;
                float mask = (m > 0.5f) ? (1.0f + 1e-7f) : 1e-7f;
                num += (1.0f - ssim) * mask;
                den += mask;
            }
        }
    }

    for (int off = 32; off > 0; off >>= 1) {
        num += __shfl_down(num, off);
        den += __shfl_down(den, off);
    }
    int wave = tid >> 6;
    int lane = tid & 63;
    if (lane == 0) { redn[wave] = num; redd[wave] = den; }
    __syncthreads();
    if (tid == 0) {
        float n = redn[0] + redn[1] + redn[2] + redn[3];
        atomicAdd(&acc[0], (double)n);
        if (c == 0) {
            float d = redd[0] + redd[1] + redd[2] + redd[3];
            atomicAdd(&acc[1], (double)d);
        }
    }
}

__global__ void finalize(const double* __restrict__ acc, float* __restrict__ out) {
    out[0] = (float)(acc[0] / acc[1] / 3.0);
}

extern "C" void kernel_launch(void* const* d_in, const int* in_sizes, int n_in,
                              void* d_out, int out_size, void* d_ws, size_t ws_size,
                              hipStream_t stream) {
    const float* img1  = (const float*)d_in[0];
    const float* img2  = (const float*)d_in[1];
    const float* match = (const float*)d_in[2];
    float* out = (float*)d_out;
    double* acc = (double*)d_ws;                       // 16 B @ ws+0

    const size_t mask_need = 128 + (size_t)BATCH * IMH * IMW;  // 4,194,432 B
    const bool premask = (ws_size >= mask_need);
    float* gw = (float*)((char*)d_ws + 64);            // 44 B @ ws+64

    // zero acc[0..1] (doubles: all-zero bytes == +0.0); capturable async op
    hipMemsetAsync(d_ws, 0, 16, stream);

    dim3 block(256, 1, 1);
    if (premask) {
        unsigned char* mbuf = (unsigned char*)d_ws + 128;
        dim3 mgrid(IMW / MTW, IMH / MTH, BATCH);               // 8 x 8 x 16
        mask_pass<<<mgrid, block, 0, stream>>>(match, mbuf, gw, acc);
        dim3 grid(IMW / STRIPW, IMH / STRIPH, BATCH * CHANS);  // 8 x 8 x 48
        ssim_main_pm<<<grid, block, 0, stream>>>(img1, img2, mbuf, gw, acc);
    } else {
        dim3 grid(IMW / STRIPW, IMH / FBSTRIPH, BATCH * CHANS);
        ssim_main_fb<<<grid, block, 0, stream>>>(img1, img2, match, acc);
    }

    finalize<<<1, 1, 0, stream>>>(acc, out);
}